// Round 13
// baseline (240.229 us; speedup 1.0000x reference)
//
#include <hip/hip_runtime.h>

// EMA Vector-Quantizer for MI355X (gfx950).
// N=16384 tokens, D=64, K=8192.
// R17-R19: fp32 VALU GEMM plateau 203us (no fp32 MFMA on CDNA4).
// R20-R23: bf16 hi/lo split GEMM on matrix pipe + exact-margin fp32 refine.
// R24: wave-per-code refine. R25: atomic-free embed (counting sort).
// R26: triple-buffer + counted vmcnt(1). R29: med3 epilogue -- VALUBusy
// dropped 53.5->48.5 but dur 73->72: k_argmin is LATENCY-bound, not
// VALU-bound (both pipes <50%, issue-work arithmetic ~11us vs 72us
// measured; 2.7 waves/SIMD can't cover ds_read+MFMA-chain latency).
// Occupancy grid-capped: 1024 blocks = 4/CU exactly.
// R30 (this): double wave supply, same total work:
//  - k_argmin: 2048 blocks x 4 waves x 16 tokens/wave (was 1024x4x32).
//    Per-wave state halves (a[4]=16, acc=4, best=12); b-frag live-range
//    split (b0/b1 -> 4 MFMAs -> b2/b3 -> 2 MFMAs) keeps VGPR <= 64 ->
//    __launch_bounds__(256,8) = 8 blocks/CU, LDS 131KB/CU.
//  - total MFMA work unchanged; B-panel L2 traffic 2x (~12% XCD L2 BW).
// Falsification: VGPR>64 or WRITE>>1.5MB = spill (abort direction);
// occupancy up but dur flat = barrier-protocol-bound (next: wave-private
// buffers).
// Scratch liveness (out buffer):
//   A' bf16[16384][128] @ 0      : prep -> k_embed, then z_q
//   B'' @ float 1056768 (2MB)    : prep -> k_argmin, then int scratch
//     FLAGS@1056768 TOK@1073152 OFFS@1089536 CURS@1097736 (all < CS)
//   cand [EA, +393216) / packed @ PK_BASE : dead before k_embed owns EA
//   counts @ OFF_CS: zeroed in k_reduce -> k_enc -> k_scan/k_embed/k_final
// Predicted: occ 34->60-70%, k_argmin 72 -> 45-55us, total ~210-222us.

#define N_TOK 16384
#define K_EMB 8192
#define EMB_D 64
#define GROUPS 8

typedef short bf8 __attribute__((ext_vector_type(8)));
typedef float f32x4 __attribute__((ext_vector_type(4)));
typedef unsigned short us4 __attribute__((ext_vector_type(4)));

// d_out flat layout (float32), reference return order:
// z_q (1048576) | loss | new_weight (524288) | new_cluster_size (8192) | new_embed_avg (524288)
#define OFF_LOSS 1048576
#define OFF_W    1048577
#define OFF_CS   1572865
#define OFF_EA   1581057

// scratch offsets
#define B_BASE   2113536   // ushort index into out = byte 4227072 (16B aligned)
#define CAND_I1  131072    // within EA-based cand area (floats/ints)
#define CAND_D2  262144
#define PK_BASE  (OFF_EA + 393217)  // even float idx -> 8B-aligned u64[16384]

// int-indexed scratch in dead-B'' (W region, consumed before k_final)
#define SCR_FLAGS 1056768
#define SCR_TOK   1073152
#define SCR_OFFS  1089536
#define SCR_CURS  1097736

#define MARGIN 0.01f

// ws float offsets
#define WS_NSUM  0
#define WS_LOSS  1
#define WS_FCNT  2        // int
#define WS_WNORM 16
#define WS_IDX   (WS_WNORM + K_EMB)   // int idx[16384]

__device__ __forceinline__ unsigned short f2bf(float x) {
  unsigned int b = __float_as_uint(x);
  return (unsigned short)((b + 0x7fff + ((b >> 16) & 1)) >> 16);
}
__device__ __forceinline__ float bf2f(unsigned short h) {
  return __uint_as_float(((unsigned int)h) << 16);
}

// async global->LDS, 16B per lane (dest = wave-uniform base + lane*16)
__device__ __forceinline__ void gload16(const void* g, void* l) {
  __builtin_amdgcn_global_load_lds(
      (const __attribute__((address_space(1))) void*)g,
      (__attribute__((address_space(3))) void*)l, 16, 0, 0);
}

// ---------------------------------------------------------------------------
// K0 (fused): blocks 0..511: wnorm[k] + B'' chunk layout + ws scalars.
// Blocks 512..575: A' = [bf16_hi | bf16_lo] per token row via LDS transpose.
__global__ void k_prep(const float* __restrict__ weight, const float* __restrict__ z,
                       float* __restrict__ out, float* __restrict__ ws) {
  __shared__ float z_s[EMB_D * 256];
  if (blockIdx.x < 512) {
    int gid = blockIdx.x * 256 + threadIdx.x;     // 0..131071
    int row = gid >> 4;                            // codebook row 0..8191
    int l16 = gid & 15;
    float4 w4 = *(const float4*)(weight + row * EMB_D + l16 * 4);
    float s = w4.x * w4.x + w4.y * w4.y + w4.z * w4.z + w4.w * w4.w;
    #pragma unroll
    for (int off = 8; off > 0; off >>= 1) s += __shfl_xor(s, off, 16);
    if (l16 == 0) ws[WS_WNORM + row] = s;

    float wv[4] = {w4.x, w4.y, w4.z, w4.w};
    us4 hi, lo;
    #pragma unroll
    for (int e = 0; e < 4; ++e) {
      unsigned short h = f2bf(wv[e]);
      hi[e] = h;
      lo[e] = f2bf(wv[e] - bf2f(h));
    }
    int d0 = l16 * 4;
    int jj = d0 & 7;                 // 0 or 4
    int lqp = (d0 >> 3) & 3;
    int sp = d0 >> 5;                // 0 or 1
    unsigned short* bp = (unsigned short*)out + B_BASE
        + (row >> 4) * 2048 + (row & 15) * 8 + lqp * 128 + jj;
    *(us4*)(bp + sp * 512) = hi;
    *(us4*)(bp + (2 + sp) * 512) = lo;

    if (gid == 0) {
      out[OFF_LOSS] = 0.f; ws[WS_LOSS] = 0.f;
      ((int*)ws)[WS_FCNT] = 0;
    }
  } else {
    const int t = threadIdx.x;
    const int pb = blockIdx.x - 512;              // 0..63
    const int b = pb >> 2;
    const int hw0 = (pb & 3) * 256;
    const float* zb = z + b * 65536 + hw0;
    #pragma unroll
    for (int i = 0; i < 16; ++i) {
      int f4 = i * 256 + t;
      int d = f4 >> 6, c4 = (f4 & 63) * 4;
      *(float4*)(z_s + d * 256 + c4) = *(const float4*)(zb + d * 1024 + c4);
    }
    __syncthreads();
    int tok = b * 1024 + hw0 + t;
    unsigned short* ap = (unsigned short*)out + tok * 128;
    #pragma unroll
    for (int j = 0; j < 16; ++j) {
      us4 hi, lo;
      #pragma unroll
      for (int e = 0; e < 4; ++e) {
        float zv = z_s[(j * 4 + e) * 256 + t];
        unsigned short h = f2bf(zv);
        hi[e] = h;
        lo[e] = f2bf(zv - bf2f(h));
      }
      *(us4*)(ap + j * 4) = hi;
      *(us4*)(ap + 64 + j * 4) = lo;
    }
  }
}

// ---------------------------------------------------------------------------
// K1: distance argmin on the matrix pipe. R30: 2048 blocks (g=bid&7 XCD
// swizzle, tok_blk=bid>>3), 4 waves x 16 tokens/wave, 8 blocks/CU.
// Per chunk: 1 gload16/thread (triple buffer, counted vmcnt), b-frag
// live-range-split 6 MFMAs, med3 exact top-2 epilogue.
__global__ __launch_bounds__(256, 8) void k_argmin(
    const short* __restrict__ A, const short* __restrict__ B,
    const float* __restrict__ wnorm, float* __restrict__ cand) {
  __shared__ __align__(16) short wbuf[3][2048];   // 3 x 4KB chunk buffers
  __shared__ __align__(16) float wn_s[1024];      // group wnorm
  const int t = threadIdx.x;
  const int lane = t & 63;
  const int wid = __builtin_amdgcn_readfirstlane(t >> 6);  // 0..3
  const int g = blockIdx.x & 7;
  const int tok_blk = blockIdx.x >> 3;            // 0..255
  const int trow0 = tok_blk * 64 + wid * 16;
  const int lr = lane & 15, lq = lane >> 4;

  // A-frags: 1 token-tile x 4 k-segs (zh k0-31, zh k32-63, zl k0-31, zl k32-63)
  bf8 a[4];
  {
    const short* ap = A + (size_t)(trow0 + lr) * 128 + lq * 8;
    #pragma unroll
    for (int s = 0; s < 4; ++s) a[s] = *(const bf8*)(ap + s * 32);
  }

  const short* bsrc = B + (size_t)g * 64 * 2048;

  *(float4*)(wn_s + t * 4) = *(const float4*)(wnorm + g * 1024 + t * 4);
  gload16(bsrc + t * 8, &wbuf[0][0] + t * 8);
  gload16(bsrc + 2048 + t * 8, &wbuf[1][0] + t * 8);
  asm volatile("s_waitcnt vmcnt(1) lgkmcnt(0)" ::: "memory");
  __builtin_amdgcn_s_barrier();

  float d1[4], d2[4]; int i1[4];
  #pragma unroll
  for (int v = 0; v < 4; ++v) { d1[v] = 3.4e38f; d2[v] = 3.4e38f; i1[v] = 0; }

  int cur = 0, stg = 2;
  for (int c = 0; c < 64; ++c) {
    if (c + 2 < 64)
      gload16(bsrc + (c + 2) * 2048 + t * 8, &wbuf[stg][0] + t * 8);

    const short* cb = &wbuf[cur][0] + lq * 128 + lr * 8;
    float wn = wn_s[c * 16 + lr];

    // b live-range split: b0/b1 (hi segs) -> 4 MFMAs -> b2/b3 (lo segs)
    bf8 b0 = *(const bf8*)(cb);
    bf8 b1 = *(const bf8*)(cb + 512);
    f32x4 acc = (f32x4)(0.f);
    acc = __builtin_amdgcn_mfma_f32_16x16x32_bf16(a[0], b0, acc, 0, 0, 0);
    acc = __builtin_amdgcn_mfma_f32_16x16x32_bf16(a[1], b1, acc, 0, 0, 0);
    acc = __builtin_amdgcn_mfma_f32_16x16x32_bf16(a[2], b0, acc, 0, 0, 0);
    acc = __builtin_amdgcn_mfma_f32_16x16x32_bf16(a[3], b1, acc, 0, 0, 0);
    bf8 b2 = *(const bf8*)(cb + 1024);
    bf8 b3 = *(const bf8*)(cb + 1536);
    acc = __builtin_amdgcn_mfma_f32_16x16x32_bf16(a[0], b2, acc, 0, 0, 0);
    acc = __builtin_amdgcn_mfma_f32_16x16x32_bf16(a[1], b3, acc, 0, 0, 0);

    const int code = g * 1024 + c * 16 + lr;
    #pragma unroll
    for (int r = 0; r < 4; ++r) {
      float d = fmaf(-2.f, acc[r], wn);
      // exact top-2 with d1<=d2 invariant: med3 gives new 2nd-min.
      d2[r] = __builtin_amdgcn_fmed3f(d1[r], d2[r], d);
      bool lt = d < d1[r];
      d1[r] = fminf(d1[r], d);
      i1[r] = lt ? code : i1[r];
    }

    if (c < 63) {
      if (c + 2 < 64) asm volatile("s_waitcnt vmcnt(1)" ::: "memory");
      else            asm volatile("s_waitcnt vmcnt(0)" ::: "memory");
      __builtin_amdgcn_s_barrier();
    }
    cur = (cur == 2) ? 0 : cur + 1;
    stg = (stg == 2) ? 0 : stg + 1;
  }

  // exact 2-min merge across the 16 code-columns (lanes sharing lq);
  // ascending chunk order + index tie-break == numpy first-min.
  #pragma unroll
  for (int m = 1; m < 16; m <<= 1) {
    #pragma unroll
    for (int v = 0; v < 4; ++v) {
      float od1 = __shfl_xor(d1[v], m, 64);
      float od2 = __shfl_xor(d2[v], m, 64);
      int   oi1 = __shfl_xor(i1[v], m, 64);
      d2[v] = fminf(fminf(d2[v], od2), fmaxf(d1[v], od1));
      bool take = (od1 < d1[v]) || (od1 == d1[v] && oi1 < i1[v]);
      d1[v] = take ? od1 : d1[v];
      i1[v] = take ? oi1 : i1[v];
    }
  }

  if (lr == 0) {                           // lanes 0,16,32,48 (lq = 0..3)
    #pragma unroll
    for (int r = 0; r < 4; ++r) {
      int token = trow0 + lq * 4 + r;
      cand[g * N_TOK + token] = d1[r];
      ((int*)cand)[CAND_I1 + g * N_TOK + token] = i1[r];
      cand[CAND_D2 + g * N_TOK + token] = d2[r];
    }
  }
}

// ---------------------------------------------------------------------------
// K2: merge GROUPS candidates (exact 2-min); packed (idx-truth) + margin
// flags; zero counts (B'' dead here; must precede k_enc).
__global__ void k_reduce(const float* __restrict__ cand, int* __restrict__ flags,
                         int* __restrict__ fcnt,
                         unsigned long long* __restrict__ packed,
                         float* __restrict__ cs) {
  int n = blockIdx.x * 256 + threadIdx.x;
  if (n < K_EMB) cs[n] = 0.f;              // counts accumulator zero
  const int* ci = (const int*)cand + CAND_I1;
  float D1 = cand[n]; int I1 = ci[n]; float D2 = cand[CAND_D2 + n];
  #pragma unroll
  for (int g = 1; g < GROUPS; ++g) {
    float d = cand[g * N_TOK + n];
    int   i = ci[g * N_TOK + n];
    float dd = cand[CAND_D2 + g * N_TOK + n];
    D2 = fminf(fminf(D2, dd), fmaxf(D1, d));
    bool take = (d < D1) || (d == D1 && i < I1);
    D1 = take ? d : D1; I1 = take ? i : I1;
  }
  if (D2 - D1 < MARGIN) {
    packed[n] = ~0ull;                     // refine will atomicMin exact vals
    int p = atomicAdd(fcnt, 1);
    flags[p] = n;
  } else {
    unsigned int bits = __float_as_uint(D1);
    unsigned int u = (bits & 0x80000000u) ? ~bits : (bits | 0x80000000u);
    packed[n] = ((unsigned long long)u << 32) | (unsigned int)I1;
  }
}

// ---------------------------------------------------------------------------
// K2b: exact fp32 refine, wave-per-code (R24 structure).
__global__ void k_refine(const float* __restrict__ z, const float* __restrict__ weight,
                         const float* __restrict__ wnorm, const int* __restrict__ flags,
                         const int* __restrict__ fcnt,
                         unsigned long long* __restrict__ packed) {
  const int cnt = *fcnt;
  const int lane = threadIdx.x & 63;
  const int wv = threadIdx.x >> 6;
  for (int w = blockIdx.x; w < cnt * 8; w += gridDim.x) {
    const int f = w >> 3, sub = w & 7;
    const int n = flags[f];
    const int b = n >> 10, hw = n & 1023;
    const float zd = z[b * 65536 + lane * 1024 + hw];
    float bd = 3.4e38f; int bi = 0;
    const int k0 = sub * 1024 + wv * 256;
    #pragma unroll 4
    for (int i = 0; i < 256; ++i) {
      const int k = k0 + i;
      float prod = zd * weight[k * EMB_D + lane];
      #pragma unroll
      for (int off = 32; off > 0; off >>= 1) prod += __shfl_xor(prod, off, 64);
      float dist = fmaf(-2.f, prod, wnorm[k]);
      if (dist < bd) { bd = dist; bi = k; }
    }
    if (lane == 0) {
      unsigned int bits = __float_as_uint(bd);
      unsigned int u = (bits & 0x80000000u) ? ~bits : (bits | 0x80000000u);
      atomicMin(packed + n, ((unsigned long long)u << 32) | (unsigned int)bi);
    }
  }
}

// ---------------------------------------------------------------------------
// K2c: idx + enc counts from packed (post-refine truth).
__global__ void k_enc(const unsigned long long* __restrict__ packed,
                      int* __restrict__ idx, float* __restrict__ cnt) {
  int n = blockIdx.x * 256 + threadIdx.x;
  int k = (int)(packed[n] & 0xffffffffull);
  idx[n] = k;
  atomicAdd(cnt + k, 1.0f);
}

// ---------------------------------------------------------------------------
// K2e: exclusive prefix-sum of counts -> offs + cursors; also nsum
// closed-form: 0.99*sum(cluster_in) + 0.01*N_TOK (sum enc == N_TOK exact).
__global__ void k_scan(const float* __restrict__ cnt,
                       const float* __restrict__ cluster_in,
                       int* __restrict__ offs, int* __restrict__ curs,
                       float* __restrict__ ws) {
  __shared__ int part[256];
  __shared__ float fpart[256];
  const int t = threadIdx.x;
  const int base = t * 32;
  int local[32];
  int s = 0;
  #pragma unroll
  for (int i = 0; i < 32; ++i) { local[i] = s; s += (int)cnt[base + i]; }
  part[t] = s;
  float csl = 0.f;
  #pragma unroll
  for (int i = 0; i < 32; ++i) csl += cluster_in[base + i];
  fpart[t] = csl;
  __syncthreads();
  if (t == 0) {
    int run = 0;
    for (int i = 0; i < 256; ++i) { int v = part[i]; part[i] = run; run += v; }
    float cs2 = 0.f;
    for (int i = 0; i < 256; ++i) cs2 += fpart[i];
    ws[WS_NSUM] = 0.99f * cs2 + 0.01f * (float)N_TOK;
  }
  __syncthreads();
  const int p = part[t];
  #pragma unroll
  for (int i = 0; i < 32; ++i) {
    offs[base + i] = p + local[i];
    curs[base + i] = p + local[i];
  }
}

// ---------------------------------------------------------------------------
// K2f: scatter token ids grouped by code (16K atomics over 8K cursors).
__global__ void k_scatter(const int* __restrict__ idx, int* __restrict__ curs,
                          int* __restrict__ toklist) {
  int n = blockIdx.x * 256 + threadIdx.x;
  int k = idx[n];
  int pos = atomicAdd(curs + k, 1);
  toklist[pos] = n;
}

// ---------------------------------------------------------------------------
// K2g: segmented embed_sum, wave per code, NO atomics. Overwrites EA
// (cand/packed dead). Runs before k_quant overwrites A'.
__global__ void k_embed(const unsigned short* __restrict__ A,
                        const float* __restrict__ cnt,
                        const int* __restrict__ offs,
                        const int* __restrict__ toklist,
                        float* __restrict__ embed) {
  const int lane = threadIdx.x & 63;
  const int k = blockIdx.x * 4 + (threadIdx.x >> 6);
  const int m = (int)cnt[k];
  const int off = offs[k];
  float s = 0.f;
  for (int i = 0; i < m; ++i) {
    const unsigned short* row = A + (size_t)toklist[off + i] * 128;
    s += bf2f(row[lane]) + bf2f(row[64 + lane]);
  }
  embed[k * EMB_D + lane] = s;
}

// ---------------------------------------------------------------------------
// K3: z_q gather + straight-through output + loss partials. x4 vectorized:
// 4 consecutive e = same (b,c), 4 consecutive tokens.
__global__ void k_quant(const float* __restrict__ z, const float* __restrict__ weight,
                        const int* __restrict__ idx, float* __restrict__ out,
                        float* __restrict__ ws) {
  int e0 = (blockIdx.x * 256 + threadIdx.x) * 4;
  int c = (e0 >> 10) & 63;
  int n0 = ((e0 >> 16) << 10) | (e0 & 1023);
  float4 zv = *(const float4*)(z + e0);
  int4 kk = *(const int4*)(idx + n0);
  float4 q;
  q.x = weight[kk.x * EMB_D + c];
  q.y = weight[kk.y * EMB_D + c];
  q.z = weight[kk.z * EMB_D + c];
  q.w = weight[kk.w * EMB_D + c];
  *(float4*)(out + e0) = q;               // straight-through value z+(q-z)=q
  float dx = q.x - zv.x, dy = q.y - zv.y, dz = q.z - zv.z, dw = q.w - zv.w;
  float lsum = dx * dx + dy * dy + dz * dz + dw * dw;
  #pragma unroll
  for (int off = 32; off > 0; off >>= 1) lsum += __shfl_xor(lsum, off, 64);
  __shared__ float red[4];
  int lane = threadIdx.x & 63, wv = threadIdx.x >> 6;
  if (lane == 0) red[wv] = lsum;
  __syncthreads();
  if (threadIdx.x == 0)
    atomicAdd(ws + WS_LOSS, red[0] + red[1] + red[2] + red[3]);
}

// ---------------------------------------------------------------------------
// K5 (fused cluster+final, x4): 4 consecutive e share one k. ncs from raw
// counts; CS written once per k by the (e0&63)==0 thread AFTER block-local
// cnt reads (block owns whole k-groups -> race-free). Loss finalized here.
__global__ void k_final(const float* __restrict__ cluster_in,
                        const float* __restrict__ embed_avg,
                        float* __restrict__ out, const float* __restrict__ ws) {
  int e0 = (blockIdx.x * 256 + threadIdx.x) * 4;   // < 524288
  int k = e0 >> 6;
  float cntk = out[OFF_CS + k];             // raw count
  float ncs = cluster_in[k] * 0.99f + 0.01f * cntk;
  float nsum = ws[WS_NSUM];
  float sm = (ncs + 1e-5f) / (nsum + K_EMB * 1e-5f) * nsum;
  float inv_sm = 1.0f / sm;
  float4 eav = *(const float4*)(embed_avg + e0);
  float4 acc = *(const float4*)(out + OFF_EA + e0);
  float4 ea;
  ea.x = eav.x * 0.99f + 0.01f * acc.x;
  ea.y = eav.y * 0.99f + 0.01f * acc.y;
  ea.z = eav.z * 0.99f + 0.01f * acc.z;
  ea.w = eav.w * 0.99f + 0.01f * acc.w;
  __syncthreads();                          // all cnt reads in block done
  if ((e0 & 63) == 0) out[OFF_CS + k] = ncs;
  *(float4*)(out + OFF_EA + e0) = ea;
  float4 w4;
  w4.x = ea.x * inv_sm; w4.y = ea.y * inv_sm;
  w4.z = ea.z * inv_sm; w4.w = ea.w * inv_sm;
  *(float4*)(out + OFF_W + e0) = w4;
  if (e0 == 0)
    out[OFF_LOSS] = 0.25f * ws[WS_LOSS] * (1.0f / 1048576.0f);
}

// ---------------------------------------------------------------------------
extern "C" void kernel_launch(void* const* d_in, const int* in_sizes, int n_in,
                              void* d_out, int out_size, void* d_ws, size_t ws_size,
                              hipStream_t stream) {
  const float* z = (const float*)d_in[0];
  const float* weight = (const float*)d_in[1];
  const float* cluster = (const float*)d_in[2];
  const float* embed_avg = (const float*)d_in[3];
  float* out = (float*)d_out;
  float* ws = (float*)d_ws;
  float* wnorm = ws + WS_WNORM;
  int* idx = (int*)(ws + WS_IDX);
  int* fcnt = (int*)ws + WS_FCNT;
  const short* Ap = (const short*)out;                     // A' in z_q region
  const short* Bp = (const short*)((unsigned short*)out + B_BASE);
  float* cand = out + OFF_EA;
  unsigned long long* packed = (unsigned long long*)(out + PK_BASE);
  int* flags = (int*)out + SCR_FLAGS;                      // dead-B'' scratch
  int* toklist = (int*)out + SCR_TOK;
  int* offs = (int*)out + SCR_OFFS;
  int* curs = (int*)out + SCR_CURS;

  hipLaunchKernelGGL(k_prep, dim3(576), dim3(256), 0, stream, weight, z, out, ws);
  hipLaunchKernelGGL(k_argmin, dim3(2048), dim3(256), 0, stream,
                     Ap, Bp, wnorm, cand);
  hipLaunchKernelGGL(k_reduce, dim3(N_TOK / 256), dim3(256), 0, stream,
                     cand, flags, fcnt, packed, out + OFF_CS);
  hipLaunchKernelGGL(k_refine, dim3(1024), dim3(256), 0, stream,
                     z, weight, wnorm, flags, fcnt, packed);
  hipLaunchKernelGGL(k_enc, dim3(N_TOK / 256), dim3(256), 0, stream,
                     packed, idx, out + OFF_CS);
  hipLaunchKernelGGL(k_scan, dim3(1), dim3(256), 0, stream,
                     out + OFF_CS, cluster, offs, curs, ws);
  hipLaunchKernelGGL(k_scatter, dim3(N_TOK / 256), dim3(256), 0, stream,
                     idx, curs, toklist);
  hipLaunchKernelGGL(k_embed, dim3(K_EMB / 4), dim3(256), 0, stream,
                     (const unsigned short*)out, out + OFF_CS, offs, toklist,
                     out + OFF_EA);
  hipLaunchKernelGGL(k_quant, dim3(1024), dim3(256), 0, stream,
                     z, weight, idx, out, ws);
  hipLaunchKernelGGL(k_final, dim3(512), dim3(256), 0, stream,
                     cluster, embed_avg, out, ws);
}

// Round 14
// 226.247 us; speedup vs baseline: 1.0618x; 1.0618x over previous
//
#include <hip/hip_runtime.h>

// EMA Vector-Quantizer for MI355X (gfx950).
// N=16384 tokens, D=64, K=8192.
// R17-R19: fp32 VALU GEMM plateau 203us (no fp32 MFMA on CDNA4).
// R20-R23: bf16 hi/lo split GEMM on matrix pipe + exact-margin fp32 refine.
// R24: wave-per-code refine. R25: atomic-free embed (counting sort).
// R26: triple-buffer + counted vmcnt(1). R29: med3 epilogue. R30: 8
// blocks/CU (occ 34->65%) -- k_argmin STILL 71us: three structural
// variants identical => k_argmin converged at ~71us (dependency-structure
// bound, no pipe saturated). Tail = ~169us over 9 kernels, unmoved.
// R31 (this): tail audit says the unaccounted 40-70us is k_embed --
// wave-per-code with SERIAL m-token loop of 2B scalar loads = max-cluster
// x ~200cy latency. Rewrite: block-per-code (8192 blocks), wave w takes
// tokens i%4==w (serial path /4, unrolled); per token ONE coalesced
// 256B wave-load (lane=4B: lanes 0-31 hi-pairs, 32-63 lo-pairs);
// shfl_xor(32) folds hi+lo; LDS folds 4 waves; wave0 stores 256B.
// toklist index wave-uniform -> s_load. All else unchanged from R30.
// Scratch liveness (out buffer):
//   A' bf16[16384][128] @ 0      : prep -> k_embed, then z_q
//   B'' @ float 1056768 (2MB)    : prep -> k_argmin, then int scratch
//     FLAGS@1056768 TOK@1073152 OFFS@1089536 CURS@1097736 (all < CS)
//   cand [EA, +393216) / packed @ PK_BASE : dead before k_embed owns EA
//   counts @ OFF_CS: zeroed in k_reduce -> k_enc -> k_scan/k_embed/k_final
// Predicted: k_argmin ~71us unchanged; total 240 -> ~185-210us.

#define N_TOK 16384
#define K_EMB 8192
#define EMB_D 64
#define GROUPS 8

typedef short bf8 __attribute__((ext_vector_type(8)));
typedef float f32x4 __attribute__((ext_vector_type(4)));
typedef unsigned short us4 __attribute__((ext_vector_type(4)));

// d_out flat layout (float32), reference return order:
// z_q (1048576) | loss | new_weight (524288) | new_cluster_size (8192) | new_embed_avg (524288)
#define OFF_LOSS 1048576
#define OFF_W    1048577
#define OFF_CS   1572865
#define OFF_EA   1581057

// scratch offsets
#define B_BASE   2113536   // ushort index into out = byte 4227072 (16B aligned)
#define CAND_I1  131072    // within EA-based cand area (floats/ints)
#define CAND_D2  262144
#define PK_BASE  (OFF_EA + 393217)  // even float idx -> 8B-aligned u64[16384]

// int-indexed scratch in dead-B'' (W region, consumed before k_final)
#define SCR_FLAGS 1056768
#define SCR_TOK   1073152
#define SCR_OFFS  1089536
#define SCR_CURS  1097736

#define MARGIN 0.01f

// ws float offsets
#define WS_NSUM  0
#define WS_LOSS  1
#define WS_FCNT  2        // int
#define WS_WNORM 16
#define WS_IDX   (WS_WNORM + K_EMB)   // int idx[16384]

__device__ __forceinline__ unsigned short f2bf(float x) {
  unsigned int b = __float_as_uint(x);
  return (unsigned short)((b + 0x7fff + ((b >> 16) & 1)) >> 16);
}
__device__ __forceinline__ float bf2f(unsigned short h) {
  return __uint_as_float(((unsigned int)h) << 16);
}

// async global->LDS, 16B per lane (dest = wave-uniform base + lane*16)
__device__ __forceinline__ void gload16(const void* g, void* l) {
  __builtin_amdgcn_global_load_lds(
      (const __attribute__((address_space(1))) void*)g,
      (__attribute__((address_space(3))) void*)l, 16, 0, 0);
}

// ---------------------------------------------------------------------------
// K0 (fused): blocks 0..511: wnorm[k] + B'' chunk layout + ws scalars.
// Blocks 512..575: A' = [bf16_hi | bf16_lo] per token row via LDS transpose.
__global__ void k_prep(const float* __restrict__ weight, const float* __restrict__ z,
                       float* __restrict__ out, float* __restrict__ ws) {
  __shared__ float z_s[EMB_D * 256];
  if (blockIdx.x < 512) {
    int gid = blockIdx.x * 256 + threadIdx.x;     // 0..131071
    int row = gid >> 4;                            // codebook row 0..8191
    int l16 = gid & 15;
    float4 w4 = *(const float4*)(weight + row * EMB_D + l16 * 4);
    float s = w4.x * w4.x + w4.y * w4.y + w4.z * w4.z + w4.w * w4.w;
    #pragma unroll
    for (int off = 8; off > 0; off >>= 1) s += __shfl_xor(s, off, 16);
    if (l16 == 0) ws[WS_WNORM + row] = s;

    float wv[4] = {w4.x, w4.y, w4.z, w4.w};
    us4 hi, lo;
    #pragma unroll
    for (int e = 0; e < 4; ++e) {
      unsigned short h = f2bf(wv[e]);
      hi[e] = h;
      lo[e] = f2bf(wv[e] - bf2f(h));
    }
    int d0 = l16 * 4;
    int jj = d0 & 7;                 // 0 or 4
    int lqp = (d0 >> 3) & 3;
    int sp = d0 >> 5;                // 0 or 1
    unsigned short* bp = (unsigned short*)out + B_BASE
        + (row >> 4) * 2048 + (row & 15) * 8 + lqp * 128 + jj;
    *(us4*)(bp + sp * 512) = hi;
    *(us4*)(bp + (2 + sp) * 512) = lo;

    if (gid == 0) {
      out[OFF_LOSS] = 0.f; ws[WS_LOSS] = 0.f;
      ((int*)ws)[WS_FCNT] = 0;
    }
  } else {
    const int t = threadIdx.x;
    const int pb = blockIdx.x - 512;              // 0..63
    const int b = pb >> 2;
    const int hw0 = (pb & 3) * 256;
    const float* zb = z + b * 65536 + hw0;
    #pragma unroll
    for (int i = 0; i < 16; ++i) {
      int f4 = i * 256 + t;
      int d = f4 >> 6, c4 = (f4 & 63) * 4;
      *(float4*)(z_s + d * 256 + c4) = *(const float4*)(zb + d * 1024 + c4);
    }
    __syncthreads();
    int tok = b * 1024 + hw0 + t;
    unsigned short* ap = (unsigned short*)out + tok * 128;
    #pragma unroll
    for (int j = 0; j < 16; ++j) {
      us4 hi, lo;
      #pragma unroll
      for (int e = 0; e < 4; ++e) {
        float zv = z_s[(j * 4 + e) * 256 + t];
        unsigned short h = f2bf(zv);
        hi[e] = h;
        lo[e] = f2bf(zv - bf2f(h));
      }
      *(us4*)(ap + j * 4) = hi;
      *(us4*)(ap + 64 + j * 4) = lo;
    }
  }
}

// ---------------------------------------------------------------------------
// K1: distance argmin on the matrix pipe (R30 structure, converged ~71us).
__global__ __launch_bounds__(256, 8) void k_argmin(
    const short* __restrict__ A, const short* __restrict__ B,
    const float* __restrict__ wnorm, float* __restrict__ cand) {
  __shared__ __align__(16) short wbuf[3][2048];   // 3 x 4KB chunk buffers
  __shared__ __align__(16) float wn_s[1024];      // group wnorm
  const int t = threadIdx.x;
  const int lane = t & 63;
  const int wid = __builtin_amdgcn_readfirstlane(t >> 6);  // 0..3
  const int g = blockIdx.x & 7;
  const int tok_blk = blockIdx.x >> 3;            // 0..255
  const int trow0 = tok_blk * 64 + wid * 16;
  const int lr = lane & 15, lq = lane >> 4;

  bf8 a[4];
  {
    const short* ap = A + (size_t)(trow0 + lr) * 128 + lq * 8;
    #pragma unroll
    for (int s = 0; s < 4; ++s) a[s] = *(const bf8*)(ap + s * 32);
  }

  const short* bsrc = B + (size_t)g * 64 * 2048;

  *(float4*)(wn_s + t * 4) = *(const float4*)(wnorm + g * 1024 + t * 4);
  gload16(bsrc + t * 8, &wbuf[0][0] + t * 8);
  gload16(bsrc + 2048 + t * 8, &wbuf[1][0] + t * 8);
  asm volatile("s_waitcnt vmcnt(1) lgkmcnt(0)" ::: "memory");
  __builtin_amdgcn_s_barrier();

  float d1[4], d2[4]; int i1[4];
  #pragma unroll
  for (int v = 0; v < 4; ++v) { d1[v] = 3.4e38f; d2[v] = 3.4e38f; i1[v] = 0; }

  int cur = 0, stg = 2;
  for (int c = 0; c < 64; ++c) {
    if (c + 2 < 64)
      gload16(bsrc + (c + 2) * 2048 + t * 8, &wbuf[stg][0] + t * 8);

    const short* cb = &wbuf[cur][0] + lq * 128 + lr * 8;
    float wn = wn_s[c * 16 + lr];

    bf8 b0 = *(const bf8*)(cb);
    bf8 b1 = *(const bf8*)(cb + 512);
    f32x4 acc = (f32x4)(0.f);
    acc = __builtin_amdgcn_mfma_f32_16x16x32_bf16(a[0], b0, acc, 0, 0, 0);
    acc = __builtin_amdgcn_mfma_f32_16x16x32_bf16(a[1], b1, acc, 0, 0, 0);
    acc = __builtin_amdgcn_mfma_f32_16x16x32_bf16(a[2], b0, acc, 0, 0, 0);
    acc = __builtin_amdgcn_mfma_f32_16x16x32_bf16(a[3], b1, acc, 0, 0, 0);
    bf8 b2 = *(const bf8*)(cb + 1024);
    bf8 b3 = *(const bf8*)(cb + 1536);
    acc = __builtin_amdgcn_mfma_f32_16x16x32_bf16(a[0], b2, acc, 0, 0, 0);
    acc = __builtin_amdgcn_mfma_f32_16x16x32_bf16(a[1], b3, acc, 0, 0, 0);

    const int code = g * 1024 + c * 16 + lr;
    #pragma unroll
    for (int r = 0; r < 4; ++r) {
      float d = fmaf(-2.f, acc[r], wn);
      d2[r] = __builtin_amdgcn_fmed3f(d1[r], d2[r], d);
      bool lt = d < d1[r];
      d1[r] = fminf(d1[r], d);
      i1[r] = lt ? code : i1[r];
    }

    if (c < 63) {
      if (c + 2 < 64) asm volatile("s_waitcnt vmcnt(1)" ::: "memory");
      else            asm volatile("s_waitcnt vmcnt(0)" ::: "memory");
      __builtin_amdgcn_s_barrier();
    }
    cur = (cur == 2) ? 0 : cur + 1;
    stg = (stg == 2) ? 0 : stg + 1;
  }

  #pragma unroll
  for (int m = 1; m < 16; m <<= 1) {
    #pragma unroll
    for (int v = 0; v < 4; ++v) {
      float od1 = __shfl_xor(d1[v], m, 64);
      float od2 = __shfl_xor(d2[v], m, 64);
      int   oi1 = __shfl_xor(i1[v], m, 64);
      d2[v] = fminf(fminf(d2[v], od2), fmaxf(d1[v], od1));
      bool take = (od1 < d1[v]) || (od1 == d1[v] && oi1 < i1[v]);
      d1[v] = take ? od1 : d1[v];
      i1[v] = take ? oi1 : i1[v];
    }
  }

  if (lr == 0) {                           // lanes 0,16,32,48 (lq = 0..3)
    #pragma unroll
    for (int r = 0; r < 4; ++r) {
      int token = trow0 + lq * 4 + r;
      cand[g * N_TOK + token] = d1[r];
      ((int*)cand)[CAND_I1 + g * N_TOK + token] = i1[r];
      cand[CAND_D2 + g * N_TOK + token] = d2[r];
    }
  }
}

// ---------------------------------------------------------------------------
// K2: merge GROUPS candidates (exact 2-min); packed (idx-truth) + margin
// flags; zero counts (B'' dead here; must precede k_enc).
__global__ void k_reduce(const float* __restrict__ cand, int* __restrict__ flags,
                         int* __restrict__ fcnt,
                         unsigned long long* __restrict__ packed,
                         float* __restrict__ cs) {
  int n = blockIdx.x * 256 + threadIdx.x;
  if (n < K_EMB) cs[n] = 0.f;              // counts accumulator zero
  const int* ci = (const int*)cand + CAND_I1;
  float D1 = cand[n]; int I1 = ci[n]; float D2 = cand[CAND_D2 + n];
  #pragma unroll
  for (int g = 1; g < GROUPS; ++g) {
    float d = cand[g * N_TOK + n];
    int   i = ci[g * N_TOK + n];
    float dd = cand[CAND_D2 + g * N_TOK + n];
    D2 = fminf(fminf(D2, dd), fmaxf(D1, d));
    bool take = (d < D1) || (d == D1 && i < I1);
    D1 = take ? d : D1; I1 = take ? i : I1;
  }
  if (D2 - D1 < MARGIN) {
    packed[n] = ~0ull;                     // refine will atomicMin exact vals
    int p = atomicAdd(fcnt, 1);
    flags[p] = n;
  } else {
    unsigned int bits = __float_as_uint(D1);
    unsigned int u = (bits & 0x80000000u) ? ~bits : (bits | 0x80000000u);
    packed[n] = ((unsigned long long)u << 32) | (unsigned int)I1;
  }
}

// ---------------------------------------------------------------------------
// K2b: exact fp32 refine, wave-per-code (R24 structure).
__global__ void k_refine(const float* __restrict__ z, const float* __restrict__ weight,
                         const float* __restrict__ wnorm, const int* __restrict__ flags,
                         const int* __restrict__ fcnt,
                         unsigned long long* __restrict__ packed) {
  const int cnt = *fcnt;
  const int lane = threadIdx.x & 63;
  const int wv = threadIdx.x >> 6;
  for (int w = blockIdx.x; w < cnt * 8; w += gridDim.x) {
    const int f = w >> 3, sub = w & 7;
    const int n = flags[f];
    const int b = n >> 10, hw = n & 1023;
    const float zd = z[b * 65536 + lane * 1024 + hw];
    float bd = 3.4e38f; int bi = 0;
    const int k0 = sub * 1024 + wv * 256;
    #pragma unroll 4
    for (int i = 0; i < 256; ++i) {
      const int k = k0 + i;
      float prod = zd * weight[k * EMB_D + lane];
      #pragma unroll
      for (int off = 32; off > 0; off >>= 1) prod += __shfl_xor(prod, off, 64);
      float dist = fmaf(-2.f, prod, wnorm[k]);
      if (dist < bd) { bd = dist; bi = k; }
    }
    if (lane == 0) {
      unsigned int bits = __float_as_uint(bd);
      unsigned int u = (bits & 0x80000000u) ? ~bits : (bits | 0x80000000u);
      atomicMin(packed + n, ((unsigned long long)u << 32) | (unsigned int)bi);
    }
  }
}

// ---------------------------------------------------------------------------
// K2c: idx + enc counts from packed (post-refine truth).
__global__ void k_enc(const unsigned long long* __restrict__ packed,
                      int* __restrict__ idx, float* __restrict__ cnt) {
  int n = blockIdx.x * 256 + threadIdx.x;
  int k = (int)(packed[n] & 0xffffffffull);
  idx[n] = k;
  atomicAdd(cnt + k, 1.0f);
}

// ---------------------------------------------------------------------------
// K2e: exclusive prefix-sum of counts -> offs + cursors; also nsum
// closed-form: 0.99*sum(cluster_in) + 0.01*N_TOK (sum enc == N_TOK exact).
__global__ void k_scan(const float* __restrict__ cnt,
                       const float* __restrict__ cluster_in,
                       int* __restrict__ offs, int* __restrict__ curs,
                       float* __restrict__ ws) {
  __shared__ int part[256];
  __shared__ float fpart[256];
  const int t = threadIdx.x;
  const int base = t * 32;
  int local[32];
  int s = 0;
  #pragma unroll
  for (int i = 0; i < 32; ++i) { local[i] = s; s += (int)cnt[base + i]; }
  part[t] = s;
  float csl = 0.f;
  #pragma unroll
  for (int i = 0; i < 32; ++i) csl += cluster_in[base + i];
  fpart[t] = csl;
  __syncthreads();
  if (t == 0) {
    int run = 0;
    for (int i = 0; i < 256; ++i) { int v = part[i]; part[i] = run; run += v; }
    float cs2 = 0.f;
    for (int i = 0; i < 256; ++i) cs2 += fpart[i];
    ws[WS_NSUM] = 0.99f * cs2 + 0.01f * (float)N_TOK;
  }
  __syncthreads();
  const int p = part[t];
  #pragma unroll
  for (int i = 0; i < 32; ++i) {
    offs[base + i] = p + local[i];
    curs[base + i] = p + local[i];
  }
}

// ---------------------------------------------------------------------------
// K2f: scatter token ids grouped by code (16K atomics over 8K cursors).
__global__ void k_scatter(const int* __restrict__ idx, int* __restrict__ curs,
                          int* __restrict__ toklist) {
  int n = blockIdx.x * 256 + threadIdx.x;
  int k = idx[n];
  int pos = atomicAdd(curs + k, 1);
  toklist[pos] = n;
}

// ---------------------------------------------------------------------------
// K2g: segmented embed_sum, BLOCK per code (R31): wave w takes tokens
// i%4==w; per token ONE coalesced 256B wave-load of the A' row (lane=4B:
// lanes 0-31 = hi bf16 pair for dims (2l,2l+1), lanes 32-63 = lo pair);
// shfl_xor(32) folds hi+lo; LDS folds the 4 waves; wave0 stores 256B.
// No atomics; worst-case serial path = m/4 (was m). Overwrites EA fully.
__global__ void k_embed(const unsigned short* __restrict__ A,
                        const float* __restrict__ cnt,
                        const int* __restrict__ offs,
                        const int* __restrict__ toklist,
                        float* __restrict__ embed) {
  __shared__ float sh[4][EMB_D];
  const int t = threadIdx.x;
  const int lane = t & 63;
  const int w = t >> 6;                    // wave 0..3
  const int k = blockIdx.x;
  const int m = (int)cnt[k];
  const int off = offs[k];

  float sA = 0.f, sB = 0.f;                // pair partials for this lane
  #pragma unroll 2
  for (int i = w; i < m; i += 4) {
    int tok = toklist[off + i];            // wave-uniform -> s_load
    unsigned v = *(const unsigned*)(A + (size_t)tok * 128 + 2 * lane);
    sA += bf2f((unsigned short)(v & 0xffffu));
    sB += bf2f((unsigned short)(v >> 16));
  }
  // fold lo-half (lanes 32-63) into hi-half lanes (0-31):
  sA += __shfl_xor(sA, 32, 64);
  sB += __shfl_xor(sB, 32, 64);
  if (lane < 32) {
    sh[w][2 * lane] = sA;
    sh[w][2 * lane + 1] = sB;
  }
  __syncthreads();
  if (t < EMB_D)
    embed[k * EMB_D + t] = sh[0][t] + sh[1][t] + sh[2][t] + sh[3][t];
}

// ---------------------------------------------------------------------------
// K3: z_q gather + straight-through output + loss partials. x4 vectorized.
__global__ void k_quant(const float* __restrict__ z, const float* __restrict__ weight,
                        const int* __restrict__ idx, float* __restrict__ out,
                        float* __restrict__ ws) {
  int e0 = (blockIdx.x * 256 + threadIdx.x) * 4;
  int c = (e0 >> 10) & 63;
  int n0 = ((e0 >> 16) << 10) | (e0 & 1023);
  float4 zv = *(const float4*)(z + e0);
  int4 kk = *(const int4*)(idx + n0);
  float4 q;
  q.x = weight[kk.x * EMB_D + c];
  q.y = weight[kk.y * EMB_D + c];
  q.z = weight[kk.z * EMB_D + c];
  q.w = weight[kk.w * EMB_D + c];
  *(float4*)(out + e0) = q;               // straight-through value z+(q-z)=q
  float dx = q.x - zv.x, dy = q.y - zv.y, dz = q.z - zv.z, dw = q.w - zv.w;
  float lsum = dx * dx + dy * dy + dz * dz + dw * dw;
  #pragma unroll
  for (int off = 32; off > 0; off >>= 1) lsum += __shfl_xor(lsum, off, 64);
  __shared__ float red[4];
  int lane = threadIdx.x & 63, wv = threadIdx.x >> 6;
  if (lane == 0) red[wv] = lsum;
  __syncthreads();
  if (threadIdx.x == 0)
    atomicAdd(ws + WS_LOSS, red[0] + red[1] + red[2] + red[3]);
}

// ---------------------------------------------------------------------------
// K5 (fused cluster+final, x4): 4 consecutive e share one k. ncs from raw
// counts; CS written once per k by the (e0&63)==0 thread AFTER block-local
// cnt reads (block owns whole k-groups -> race-free). Loss finalized here.
__global__ void k_final(const float* __restrict__ cluster_in,
                        const float* __restrict__ embed_avg,
                        float* __restrict__ out, const float* __restrict__ ws) {
  int e0 = (blockIdx.x * 256 + threadIdx.x) * 4;   // < 524288
  int k = e0 >> 6;
  float cntk = out[OFF_CS + k];             // raw count
  float ncs = cluster_in[k] * 0.99f + 0.01f * cntk;
  float nsum = ws[WS_NSUM];
  float sm = (ncs + 1e-5f) / (nsum + K_EMB * 1e-5f) * nsum;
  float inv_sm = 1.0f / sm;
  float4 eav = *(const float4*)(embed_avg + e0);
  float4 acc = *(const float4*)(out + OFF_EA + e0);
  float4 ea;
  ea.x = eav.x * 0.99f + 0.01f * acc.x;
  ea.y = eav.y * 0.99f + 0.01f * acc.y;
  ea.z = eav.z * 0.99f + 0.01f * acc.z;
  ea.w = eav.w * 0.99f + 0.01f * acc.w;
  __syncthreads();                          // all cnt reads in block done
  if ((e0 & 63) == 0) out[OFF_CS + k] = ncs;
  *(float4*)(out + OFF_EA + e0) = ea;
  float4 w4;
  w4.x = ea.x * inv_sm; w4.y = ea.y * inv_sm;
  w4.z = ea.z * inv_sm; w4.w = ea.w * inv_sm;
  *(float4*)(out + OFF_W + e0) = w4;
  if (e0 == 0)
    out[OFF_LOSS] = 0.25f * ws[WS_LOSS] * (1.0f / 1048576.0f);
}

// ---------------------------------------------------------------------------
extern "C" void kernel_launch(void* const* d_in, const int* in_sizes, int n_in,
                              void* d_out, int out_size, void* d_ws, size_t ws_size,
                              hipStream_t stream) {
  const float* z = (const float*)d_in[0];
  const float* weight = (const float*)d_in[1];
  const float* cluster = (const float*)d_in[2];
  const float* embed_avg = (const float*)d_in[3];
  float* out = (float*)d_out;
  float* ws = (float*)d_ws;
  float* wnorm = ws + WS_WNORM;
  int* idx = (int*)(ws + WS_IDX);
  int* fcnt = (int*)ws + WS_FCNT;
  const short* Ap = (const short*)out;                     // A' in z_q region
  const short* Bp = (const short*)((unsigned short*)out + B_BASE);
  float* cand = out + OFF_EA;
  unsigned long long* packed = (unsigned long long*)(out + PK_BASE);
  int* flags = (int*)out + SCR_FLAGS;                      // dead-B'' scratch
  int* toklist = (int*)out + SCR_TOK;
  int* offs = (int*)out + SCR_OFFS;
  int* curs = (int*)out + SCR_CURS;

  hipLaunchKernelGGL(k_prep, dim3(576), dim3(256), 0, stream, weight, z, out, ws);
  hipLaunchKernelGGL(k_argmin, dim3(2048), dim3(256), 0, stream,
                     Ap, Bp, wnorm, cand);
  hipLaunchKernelGGL(k_reduce, dim3(N_TOK / 256), dim3(256), 0, stream,
                     cand, flags, fcnt, packed, out + OFF_CS);
  hipLaunchKernelGGL(k_refine, dim3(1024), dim3(256), 0, stream,
                     z, weight, wnorm, flags, fcnt, packed);
  hipLaunchKernelGGL(k_enc, dim3(N_TOK / 256), dim3(256), 0, stream,
                     packed, idx, out + OFF_CS);
  hipLaunchKernelGGL(k_scan, dim3(1), dim3(256), 0, stream,
                     out + OFF_CS, cluster, offs, curs, ws);
  hipLaunchKernelGGL(k_scatter, dim3(N_TOK / 256), dim3(256), 0, stream,
                     idx, curs, toklist);
  hipLaunchKernelGGL(k_embed, dim3(K_EMB), dim3(256), 0, stream,
                     (const unsigned short*)out, out + OFF_CS, offs, toklist,
                     out + OFF_EA);
  hipLaunchKernelGGL(k_quant, dim3(1024), dim3(256), 0, stream,
                     z, weight, idx, out, ws);
  hipLaunchKernelGGL(k_final, dim3(512), dim3(256), 0, stream,
                     cluster, embed_avg, out, ws);
}

// Round 16
// 223.438 us; speedup vs baseline: 1.0751x; 1.0126x over previous
//
#include <hip/hip_runtime.h>

// EMA Vector-Quantizer for MI355X (gfx950).
// N=16384 tokens, D=64, K=8192.
// R17-R19: fp32 VALU GEMM plateau 203us. R20-R23: bf16 hi/lo split GEMM on
// matrix pipe + exact-margin fp32 refine. R24: wave-per-code refine.
// R25: atomic-free embed. R26/R29/R30: argmin converged ~71-73us.
// R31: embed block-per-code -> 226.2us (verified).
// R32 (FAILED, reverted): cooperative mega-kernel fusion. Output 2 read
// STALE cnt: CS-region lines were cached on every XCD during S0 (B'' panel
// tail aliases CS); grid.sync()'s fence did not invalidate clean stale L2
// lines on gfx950 -> plain cross-stage loads unsound (guide G16). Lesson:
// per-XCD L2 non-coherence forbids mega-kernel fusion with plain
// loads/stores through aliased scratch; stream-ordered launches are the
// sanctioned coherence points.
// R33 (this): R31 exactly, + A'-prep re-grid: 64 -> 256 blocks (64 tokens
// per block, z_s 16KB; per-wave jq uniform, z_s reads conflict-free; write
// layout byte-identical). k_prep grid 576 -> 768.
// Scratch liveness (out buffer):
//   A' bf16[16384][128] @ 0      : prep -> k_embed, then z_q
//   B'' @ float 1056768 (2MB)    : prep -> k_argmin, then int scratch
//     FLAGS@1056768 TOK@1073152 OFFS@1089536 CURS@1097736 (all < CS)
//   cand [EA, +393216) / packed @ PK_BASE : dead before k_embed owns EA
//   counts @ OFF_CS: zeroed in k_reduce -> k_enc -> k_scan/k_embed/k_final
// Predicted: pass; k_argmin ~73us unchanged; total ~215-222us.

#define N_TOK 16384
#define K_EMB 8192
#define EMB_D 64
#define GROUPS 8

typedef short bf8 __attribute__((ext_vector_type(8)));
typedef float f32x4 __attribute__((ext_vector_type(4)));
typedef unsigned short us4 __attribute__((ext_vector_type(4)));

// d_out flat layout (float32), reference return order:
// z_q (1048576) | loss | new_weight (524288) | new_cluster_size (8192) | new_embed_avg (524288)
#define OFF_LOSS 1048576
#define OFF_W    1048577
#define OFF_CS   1572865
#define OFF_EA   1581057

// scratch offsets
#define B_BASE   2113536   // ushort index into out = byte 4227072 (16B aligned)
#define CAND_I1  131072    // within EA-based cand area (floats/ints)
#define CAND_D2  262144
#define PK_BASE  (OFF_EA + 393217)  // even float idx -> 8B-aligned u64[16384]

// int-indexed scratch in dead-B'' (W region, consumed before k_final)
#define SCR_FLAGS 1056768
#define SCR_TOK   1073152
#define SCR_OFFS  1089536
#define SCR_CURS  1097736

#define MARGIN 0.01f

// ws float offsets
#define WS_NSUM  0
#define WS_LOSS  1
#define WS_FCNT  2        // int
#define WS_WNORM 16
#define WS_IDX   (WS_WNORM + K_EMB)   // int idx[16384]

__device__ __forceinline__ unsigned short f2bf(float x) {
  unsigned int b = __float_as_uint(x);
  return (unsigned short)((b + 0x7fff + ((b >> 16) & 1)) >> 16);
}
__device__ __forceinline__ float bf2f(unsigned short h) {
  return __uint_as_float(((unsigned int)h) << 16);
}

// async global->LDS, 16B per lane (dest = wave-uniform base + lane*16)
__device__ __forceinline__ void gload16(const void* g, void* l) {
  __builtin_amdgcn_global_load_lds(
      (const __attribute__((address_space(1))) void*)g,
      (__attribute__((address_space(3))) void*)l, 16, 0, 0);
}

// ---------------------------------------------------------------------------
// K0 (fused): blocks 0..511: wnorm[k] + B'' chunk layout + ws scalars.
// Blocks 512..767: A' = [bf16_hi | bf16_lo], 64 tokens/block (R33 re-grid).
__global__ void k_prep(const float* __restrict__ weight, const float* __restrict__ z,
                       float* __restrict__ out, float* __restrict__ ws) {
  __shared__ float z_s[64 * 64];                  // 16KB (A'-branch only)
  if (blockIdx.x < 512) {
    int gid = blockIdx.x * 256 + threadIdx.x;     // 0..131071
    int row = gid >> 4;                            // codebook row 0..8191
    int l16 = gid & 15;
    float4 w4 = *(const float4*)(weight + row * EMB_D + l16 * 4);
    float s = w4.x * w4.x + w4.y * w4.y + w4.z * w4.z + w4.w * w4.w;
    #pragma unroll
    for (int off = 8; off > 0; off >>= 1) s += __shfl_xor(s, off, 16);
    if (l16 == 0) ws[WS_WNORM + row] = s;

    float wv[4] = {w4.x, w4.y, w4.z, w4.w};
    us4 hi, lo;
    #pragma unroll
    for (int e = 0; e < 4; ++e) {
      unsigned short h = f2bf(wv[e]);
      hi[e] = h;
      lo[e] = f2bf(wv[e] - bf2f(h));
    }
    int d0 = l16 * 4;
    int jj = d0 & 7;                 // 0 or 4
    int lqp = (d0 >> 3) & 3;
    int sp = d0 >> 5;                // 0 or 1
    unsigned short* bp = (unsigned short*)out + B_BASE
        + (row >> 4) * 2048 + (row & 15) * 8 + lqp * 128 + jj;
    *(us4*)(bp + sp * 512) = hi;
    *(us4*)(bp + (2 + sp) * 512) = lo;

    if (gid == 0) {
      out[OFF_LOSS] = 0.f; ws[WS_LOSS] = 0.f;
      ((int*)ws)[WS_FCNT] = 0;
    }
  } else {
    const int t = threadIdx.x;
    const int pb = blockIdx.x - 512;              // 0..255
    const int b = pb >> 4;                        // batch 0..15
    const int hw0 = (pb & 15) * 64;               // hw chunk of 64
    const float* zb = z + b * 65536 + hw0;
    // load 64 d x 64 hw floats: 1024 float4s, 256 threads x 4 iters
    #pragma unroll
    for (int i = 0; i < 4; ++i) {
      int f4 = i * 256 + t;
      int d = f4 >> 4, c4 = (f4 & 15) * 4;
      *(float4*)(z_s + d * 64 + c4) = *(const float4*)(zb + d * 1024 + c4);
    }
    __syncthreads();
    // wave w handles j-quarter w for all 64 tokens (lane = token)
    const int tokl = t & 63;
    const int jq = t >> 6;                        // 0..3, wave-uniform
    int tok = b * 1024 + hw0 + tokl;
    unsigned short* ap = (unsigned short*)out + (size_t)tok * 128;
    #pragma unroll
    for (int j = jq * 4; j < jq * 4 + 4; ++j) {
      us4 hi, lo;
      #pragma unroll
      for (int e = 0; e < 4; ++e) {
        float zv = z_s[(j * 4 + e) * 64 + tokl];
        unsigned short h = f2bf(zv);
        hi[e] = h;
        lo[e] = f2bf(zv - bf2f(h));
      }
      *(us4*)(ap + j * 4) = hi;
      *(us4*)(ap + 64 + j * 4) = lo;
    }
  }
}

// ---------------------------------------------------------------------------
// K1: distance argmin on the matrix pipe (R30 structure, converged ~73us).
__global__ __launch_bounds__(256, 8) void k_argmin(
    const short* __restrict__ A, const short* __restrict__ B,
    const float* __restrict__ wnorm, float* __restrict__ cand) {
  __shared__ __align__(16) short wbuf[3][2048];   // 3 x 4KB chunk buffers
  __shared__ __align__(16) float wn_s[1024];      // group wnorm
  const int t = threadIdx.x;
  const int lane = t & 63;
  const int wid = __builtin_amdgcn_readfirstlane(t >> 6);  // 0..3
  const int g = blockIdx.x & 7;
  const int tok_blk = blockIdx.x >> 3;            // 0..255
  const int trow0 = tok_blk * 64 + wid * 16;
  const int lr = lane & 15, lq = lane >> 4;

  bf8 a[4];
  {
    const short* ap = A + (size_t)(trow0 + lr) * 128 + lq * 8;
    #pragma unroll
    for (int s = 0; s < 4; ++s) a[s] = *(const bf8*)(ap + s * 32);
  }

  const short* bsrc = B + (size_t)g * 64 * 2048;

  *(float4*)(wn_s + t * 4) = *(const float4*)(wnorm + g * 1024 + t * 4);
  gload16(bsrc + t * 8, &wbuf[0][0] + t * 8);
  gload16(bsrc + 2048 + t * 8, &wbuf[1][0] + t * 8);
  asm volatile("s_waitcnt vmcnt(1) lgkmcnt(0)" ::: "memory");
  __builtin_amdgcn_s_barrier();

  float d1[4], d2[4]; int i1[4];
  #pragma unroll
  for (int v = 0; v < 4; ++v) { d1[v] = 3.4e38f; d2[v] = 3.4e38f; i1[v] = 0; }

  int cur = 0, stg = 2;
  for (int c = 0; c < 64; ++c) {
    if (c + 2 < 64)
      gload16(bsrc + (c + 2) * 2048 + t * 8, &wbuf[stg][0] + t * 8);

    const short* cb = &wbuf[cur][0] + lq * 128 + lr * 8;
    float wn = wn_s[c * 16 + lr];

    bf8 b0 = *(const bf8*)(cb);
    bf8 b1 = *(const bf8*)(cb + 512);
    f32x4 acc = (f32x4)(0.f);
    acc = __builtin_amdgcn_mfma_f32_16x16x32_bf16(a[0], b0, acc, 0, 0, 0);
    acc = __builtin_amdgcn_mfma_f32_16x16x32_bf16(a[1], b1, acc, 0, 0, 0);
    acc = __builtin_amdgcn_mfma_f32_16x16x32_bf16(a[2], b0, acc, 0, 0, 0);
    acc = __builtin_amdgcn_mfma_f32_16x16x32_bf16(a[3], b1, acc, 0, 0, 0);
    bf8 b2 = *(const bf8*)(cb + 1024);
    bf8 b3 = *(const bf8*)(cb + 1536);
    acc = __builtin_amdgcn_mfma_f32_16x16x32_bf16(a[0], b2, acc, 0, 0, 0);
    acc = __builtin_amdgcn_mfma_f32_16x16x32_bf16(a[1], b3, acc, 0, 0, 0);

    const int code = g * 1024 + c * 16 + lr;
    #pragma unroll
    for (int r = 0; r < 4; ++r) {
      float d = fmaf(-2.f, acc[r], wn);
      d2[r] = __builtin_amdgcn_fmed3f(d1[r], d2[r], d);
      bool lt = d < d1[r];
      d1[r] = fminf(d1[r], d);
      i1[r] = lt ? code : i1[r];
    }

    if (c < 63) {
      if (c + 2 < 64) asm volatile("s_waitcnt vmcnt(1)" ::: "memory");
      else            asm volatile("s_waitcnt vmcnt(0)" ::: "memory");
      __builtin_amdgcn_s_barrier();
    }
    cur = (cur == 2) ? 0 : cur + 1;
    stg = (stg == 2) ? 0 : stg + 1;
  }

  #pragma unroll
  for (int m = 1; m < 16; m <<= 1) {
    #pragma unroll
    for (int v = 0; v < 4; ++v) {
      float od1 = __shfl_xor(d1[v], m, 64);
      float od2 = __shfl_xor(d2[v], m, 64);
      int   oi1 = __shfl_xor(i1[v], m, 64);
      d2[v] = fminf(fminf(d2[v], od2), fmaxf(d1[v], od1));
      bool take = (od1 < d1[v]) || (od1 == d1[v] && oi1 < i1[v]);
      d1[v] = take ? od1 : d1[v];
      i1[v] = take ? oi1 : i1[v];
    }
  }

  if (lr == 0) {                           // lanes 0,16,32,48 (lq = 0..3)
    #pragma unroll
    for (int r = 0; r < 4; ++r) {
      int token = trow0 + lq * 4 + r;
      cand[g * N_TOK + token] = d1[r];
      ((int*)cand)[CAND_I1 + g * N_TOK + token] = i1[r];
      cand[CAND_D2 + g * N_TOK + token] = d2[r];
    }
  }
}

// ---------------------------------------------------------------------------
// K2: merge GROUPS candidates (exact 2-min); packed (idx-truth) + margin
// flags; zero counts (B'' dead here; must precede k_enc).
__global__ void k_reduce(const float* __restrict__ cand, int* __restrict__ flags,
                         int* __restrict__ fcnt,
                         unsigned long long* __restrict__ packed,
                         float* __restrict__ cs) {
  int n = blockIdx.x * 256 + threadIdx.x;
  if (n < K_EMB) cs[n] = 0.f;              // counts accumulator zero
  const int* ci = (const int*)cand + CAND_I1;
  float D1 = cand[n]; int I1 = ci[n]; float D2 = cand[CAND_D2 + n];
  #pragma unroll
  for (int g = 1; g < GROUPS; ++g) {
    float d = cand[g * N_TOK + n];
    int   i = ci[g * N_TOK + n];
    float dd = cand[CAND_D2 + g * N_TOK + n];
    D2 = fminf(fminf(D2, dd), fmaxf(D1, d));
    bool take = (d < D1) || (d == D1 && i < I1);
    D1 = take ? d : D1; I1 = take ? i : I1;
  }
  if (D2 - D1 < MARGIN) {
    packed[n] = ~0ull;                     // refine will atomicMin exact vals
    int p = atomicAdd(fcnt, 1);
    flags[p] = n;
  } else {
    unsigned int bits = __float_as_uint(D1);
    unsigned int u = (bits & 0x80000000u) ? ~bits : (bits | 0x80000000u);
    packed[n] = ((unsigned long long)u << 32) | (unsigned int)I1;
  }
}

// ---------------------------------------------------------------------------
// K2b: exact fp32 refine, wave-per-code (R24 structure).
__global__ void k_refine(const float* __restrict__ z, const float* __restrict__ weight,
                         const float* __restrict__ wnorm, const int* __restrict__ flags,
                         const int* __restrict__ fcnt,
                         unsigned long long* __restrict__ packed) {
  const int cnt = *fcnt;
  const int lane = threadIdx.x & 63;
  const int wv = threadIdx.x >> 6;
  for (int w = blockIdx.x; w < cnt * 8; w += gridDim.x) {
    const int f = w >> 3, sub = w & 7;
    const int n = flags[f];
    const int b = n >> 10, hw = n & 1023;
    const float zd = z[b * 65536 + lane * 1024 + hw];
    float bd = 3.4e38f; int bi = 0;
    const int k0 = sub * 1024 + wv * 256;
    #pragma unroll 4
    for (int i = 0; i < 256; ++i) {
      const int k = k0 + i;
      float prod = zd * weight[k * EMB_D + lane];
      #pragma unroll
      for (int off = 32; off > 0; off >>= 1) prod += __shfl_xor(prod, off, 64);
      float dist = fmaf(-2.f, prod, wnorm[k]);
      if (dist < bd) { bd = dist; bi = k; }
    }
    if (lane == 0) {
      unsigned int bits = __float_as_uint(bd);
      unsigned int u = (bits & 0x80000000u) ? ~bits : (bits | 0x80000000u);
      atomicMin(packed + n, ((unsigned long long)u << 32) | (unsigned int)bi);
    }
  }
}

// ---------------------------------------------------------------------------
// K2c: idx + enc counts from packed (post-refine truth).
__global__ void k_enc(const unsigned long long* __restrict__ packed,
                      int* __restrict__ idx, float* __restrict__ cnt) {
  int n = blockIdx.x * 256 + threadIdx.x;
  int k = (int)(packed[n] & 0xffffffffull);
  idx[n] = k;
  atomicAdd(cnt + k, 1.0f);
}

// ---------------------------------------------------------------------------
// K2e: exclusive prefix-sum of counts -> offs + cursors; also nsum
// closed-form: 0.99*sum(cluster_in) + 0.01*N_TOK (sum enc == N_TOK exact).
__global__ void k_scan(const float* __restrict__ cnt,
                       const float* __restrict__ cluster_in,
                       int* __restrict__ offs, int* __restrict__ curs,
                       float* __restrict__ ws) {
  __shared__ int part[256];
  __shared__ float fpart[256];
  const int t = threadIdx.x;
  const int base = t * 32;
  int local[32];
  int s = 0;
  #pragma unroll
  for (int i = 0; i < 32; ++i) { local[i] = s; s += (int)cnt[base + i]; }
  part[t] = s;
  float csl = 0.f;
  #pragma unroll
  for (int i = 0; i < 32; ++i) csl += cluster_in[base + i];
  fpart[t] = csl;
  __syncthreads();
  if (t == 0) {
    int run = 0;
    for (int i = 0; i < 256; ++i) { int v = part[i]; part[i] = run; run += v; }
    float cs2 = 0.f;
    for (int i = 0; i < 256; ++i) cs2 += fpart[i];
    ws[WS_NSUM] = 0.99f * cs2 + 0.01f * (float)N_TOK;
  }
  __syncthreads();
  const int p = part[t];
  #pragma unroll
  for (int i = 0; i < 32; ++i) {
    offs[base + i] = p + local[i];
    curs[base + i] = p + local[i];
  }
}

// ---------------------------------------------------------------------------
// K2f: scatter token ids grouped by code (16K atomics over 8K cursors).
__global__ void k_scatter(const int* __restrict__ idx, int* __restrict__ curs,
                          int* __restrict__ toklist) {
  int n = blockIdx.x * 256 + threadIdx.x;
  int k = idx[n];
  int pos = atomicAdd(curs + k, 1);
  toklist[pos] = n;
}

// ---------------------------------------------------------------------------
// K2g: segmented embed_sum, BLOCK per code: wave w takes tokens i%4==w;
// per token ONE coalesced 256B wave-load of the A' row (lane=4B: lanes
// 0-31 hi pairs, 32-63 lo pairs); shfl_xor(32) folds hi+lo; LDS folds
// 4 waves; store 256B. No atomics. Overwrites EA fully.
__global__ void k_embed(const unsigned short* __restrict__ A,
                        const float* __restrict__ cnt,
                        const int* __restrict__ offs,
                        const int* __restrict__ toklist,
                        float* __restrict__ embed) {
  __shared__ float sh[4][EMB_D];
  const int t = threadIdx.x;
  const int lane = t & 63;
  const int w = t >> 6;                    // wave 0..3
  const int k = blockIdx.x;
  const int m = (int)cnt[k];
  const int off = offs[k];

  float sA = 0.f, sB = 0.f;                // pair partials for this lane
  #pragma unroll 2
  for (int i = w; i < m; i += 4) {
    int tok = toklist[off + i];            // wave-uniform -> s_load
    unsigned v = *(const unsigned*)(A + (size_t)tok * 128 + 2 * lane);
    sA += bf2f((unsigned short)(v & 0xffffu));
    sB += bf2f((unsigned short)(v >> 16));
  }
  sA += __shfl_xor(sA, 32, 64);
  sB += __shfl_xor(sB, 32, 64);
  if (lane < 32) {
    sh[w][2 * lane] = sA;
    sh[w][2 * lane + 1] = sB;
  }
  __syncthreads();
  if (t < EMB_D)
    embed[k * EMB_D + t] = sh[0][t] + sh[1][t] + sh[2][t] + sh[3][t];
}

// ---------------------------------------------------------------------------
// K3: z_q gather + straight-through output + loss partials. x4 vectorized.
__global__ void k_quant(const float* __restrict__ z, const float* __restrict__ weight,
                        const int* __restrict__ idx, float* __restrict__ out,
                        float* __restrict__ ws) {
  int e0 = (blockIdx.x * 256 + threadIdx.x) * 4;
  int c = (e0 >> 10) & 63;
  int n0 = ((e0 >> 16) << 10) | (e0 & 1023);
  float4 zv = *(const float4*)(z + e0);
  int4 kk = *(const int4*)(idx + n0);
  float4 q;
  q.x = weight[kk.x * EMB_D + c];
  q.y = weight[kk.y * EMB_D + c];
  q.z = weight[kk.z * EMB_D + c];
  q.w = weight[kk.w * EMB_D + c];
  *(float4*)(out + e0) = q;               // straight-through value z+(q-z)=q
  float dx = q.x - zv.x, dy = q.y - zv.y, dz = q.z - zv.z, dw = q.w - zv.w;
  float lsum = dx * dx + dy * dy + dz * dz + dw * dw;
  #pragma unroll
  for (int off = 32; off > 0; off >>= 1) lsum += __shfl_xor(lsum, off, 64);
  __shared__ float red[4];
  int lane = threadIdx.x & 63, wv = threadIdx.x >> 6;
  if (lane == 0) red[wv] = lsum;
  __syncthreads();
  if (threadIdx.x == 0)
    atomicAdd(ws + WS_LOSS, red[0] + red[1] + red[2] + red[3]);
}

// ---------------------------------------------------------------------------
// K5 (fused cluster+final, x4): 4 consecutive e share one k. ncs from raw
// counts; CS written once per k by the (e0&63)==0 thread AFTER block-local
// cnt reads (block owns whole k-groups -> race-free). Loss finalized here.
__global__ void k_final(const float* __restrict__ cluster_in,
                        const float* __restrict__ embed_avg,
                        float* __restrict__ out, const float* __restrict__ ws) {
  int e0 = (blockIdx.x * 256 + threadIdx.x) * 4;   // < 524288
  int k = e0 >> 6;
  float cntk = out[OFF_CS + k];             // raw count
  float ncs = cluster_in[k] * 0.99f + 0.01f * cntk;
  float nsum = ws[WS_NSUM];
  float sm = (ncs + 1e-5f) / (nsum + K_EMB * 1e-5f) * nsum;
  float inv_sm = 1.0f / sm;
  float4 eav = *(const float4*)(embed_avg + e0);
  float4 acc = *(const float4*)(out + OFF_EA + e0);
  float4 ea;
  ea.x = eav.x * 0.99f + 0.01f * acc.x;
  ea.y = eav.y * 0.99f + 0.01f * acc.y;
  ea.z = eav.z * 0.99f + 0.01f * acc.z;
  ea.w = eav.w * 0.99f + 0.01f * acc.w;
  __syncthreads();                          // all cnt reads in block done
  if ((e0 & 63) == 0) out[OFF_CS + k] = ncs;
  *(float4*)(out + OFF_EA + e0) = ea;
  float4 w4;
  w4.x = ea.x * inv_sm; w4.y = ea.y * inv_sm;
  w4.z = ea.z * inv_sm; w4.w = ea.w * inv_sm;
  *(float4*)(out + OFF_W + e0) = w4;
  if (e0 == 0)
    out[OFF_LOSS] = 0.25f * ws[WS_LOSS] * (1.0f / 1048576.0f);
}

// ---------------------------------------------------------------------------
extern "C" void kernel_launch(void* const* d_in, const int* in_sizes, int n_in,
                              void* d_out, int out_size, void* d_ws, size_t ws_size,
                              hipStream_t stream) {
  const float* z = (const float*)d_in[0];
  const float* weight = (const float*)d_in[1];
  const float* cluster = (const float*)d_in[2];
  const float* embed_avg = (const float*)d_in[3];
  float* out = (float*)d_out;
  float* ws = (float*)d_ws;
  float* wnorm = ws + WS_WNORM;
  int* idx = (int*)(ws + WS_IDX);
  int* fcnt = (int*)ws + WS_FCNT;
  const short* Ap = (const short*)out;                     // A' in z_q region
  const short* Bp = (const short*)((unsigned short*)out + B_BASE);
  float* cand = out + OFF_EA;
  unsigned long long* packed = (unsigned long long*)(out + PK_BASE);
  int* flags = (int*)out + SCR_FLAGS;                      // dead-B'' scratch
  int* toklist = (int*)out + SCR_TOK;
  int* offs = (int*)out + SCR_OFFS;
  int* curs = (int*)out + SCR_CURS;

  hipLaunchKernelGGL(k_prep, dim3(768), dim3(256), 0, stream, weight, z, out, ws);
  hipLaunchKernelGGL(k_argmin, dim3(2048), dim3(256), 0, stream,
                     Ap, Bp, wnorm, cand);
  hipLaunchKernelGGL(k_reduce, dim3(N_TOK / 256), dim3(256), 0, stream,
                     cand, flags, fcnt, packed, out + OFF_CS);
  hipLaunchKernelGGL(k_refine, dim3(1024), dim3(256), 0, stream,
                     z, weight, wnorm, flags, fcnt, packed);
  hipLaunchKernelGGL(k_enc, dim3(N_TOK / 256), dim3(256), 0, stream,
                     packed, idx, out + OFF_CS);
  hipLaunchKernelGGL(k_scan, dim3(1), dim3(256), 0, stream,
                     out + OFF_CS, cluster, offs, curs, ws);
  hipLaunchKernelGGL(k_scatter, dim3(N_TOK / 256), dim3(256), 0, stream,
                     idx, curs, toklist);
  hipLaunchKernelGGL(k_embed, dim3(K_EMB), dim3(256), 0, stream,
                     (const unsigned short*)out, out + OFF_CS, offs, toklist,
                     out + OFF_EA);
  hipLaunchKernelGGL(k_quant, dim3(1024), dim3(256), 0, stream,
                     z, weight, idx, out, ws);
  hipLaunchKernelGGL(k_final, dim3(512), dim3(256), 0, stream,
                     cluster, embed_avg, out, ws);
}

// Round 17
// 194.589 us; speedup vs baseline: 1.2345x; 1.1483x over previous
//
#include <hip/hip_runtime.h>

// EMA Vector-Quantizer for MI355X (gfx950).
// N=16384 tokens, D=64, K=8192.
// R17-R19: fp32 VALU GEMM plateau 203us. R20-R23: bf16 hi/lo split GEMM on
// matrix pipe + exact-margin fp32 refine. R24: wave-per-code refine.
// R25: atomic-free embed. R26/R29/R30: argmin converged ~71-73us.
// R31: embed block-per-code. R32 (failed): coop mega-kernel -- per-XCD L2
// staleness (G16). R33: A'-prep re-grid -> 223.4us.
// R34 (this): the ~80us accounting hole is k_refine. Order-statistics: for
// random data the 1st-2nd minimum gap over 8192 codes is ~2-3e-3, so
// MARGIN=0.01 flags ~1.5-2K tokens; current refine costs ~4us/work-item
// (256 codes x 6-level 64-lane butterfly) -> 12-16 rounds over 1024 blocks
// ~= 50-70us, hiding just under k_argmin's 72 in top-5. Fix: 16-lane-group
// refine -- wave evaluates 4 codes/iter (group g owns code k+g; lane holds
// 4 dims as float4; 1KB/iter coalesced), reduce = 4-level shfl within 16
// lanes; cross-group merge 2 butterfly steps with index tie-break (numpy
// first-min kept). Grid 2048. ~4x throughput/wave, MARGIN unchanged.
// Scratch liveness (out buffer):
//   A' bf16[16384][128] @ 0      : prep -> k_embed, then z_q
//   B'' @ float 1056768 (2MB)    : prep -> k_argmin, then int scratch
//     FLAGS@1056768 TOK@1073152 OFFS@1089536 CURS@1097736 (all < CS)
//   cand [EA, +393216) / packed @ PK_BASE : dead before k_embed owns EA
//   counts @ OFF_CS: zeroed in k_reduce -> k_enc -> k_scan/k_embed/k_final
// Predicted: k_argmin ~72.5 unchanged; total 223.4 -> ~175-195us.
// Falsification: <10us move => refine theory wrong; next round instrument
// (inflate MARGIN to surface refine in top-5).

#define N_TOK 16384
#define K_EMB 8192
#define EMB_D 64
#define GROUPS 8

typedef short bf8 __attribute__((ext_vector_type(8)));
typedef float f32x4 __attribute__((ext_vector_type(4)));
typedef unsigned short us4 __attribute__((ext_vector_type(4)));

// d_out flat layout (float32), reference return order:
// z_q (1048576) | loss | new_weight (524288) | new_cluster_size (8192) | new_embed_avg (524288)
#define OFF_LOSS 1048576
#define OFF_W    1048577
#define OFF_CS   1572865
#define OFF_EA   1581057

// scratch offsets
#define B_BASE   2113536   // ushort index into out = byte 4227072 (16B aligned)
#define CAND_I1  131072    // within EA-based cand area (floats/ints)
#define CAND_D2  262144
#define PK_BASE  (OFF_EA + 393217)  // even float idx -> 8B-aligned u64[16384]

// int-indexed scratch in dead-B'' (W region, consumed before k_final)
#define SCR_FLAGS 1056768
#define SCR_TOK   1073152
#define SCR_OFFS  1089536
#define SCR_CURS  1097736

#define MARGIN 0.01f

// ws float offsets
#define WS_NSUM  0
#define WS_LOSS  1
#define WS_FCNT  2        // int
#define WS_WNORM 16
#define WS_IDX   (WS_WNORM + K_EMB)   // int idx[16384]

__device__ __forceinline__ unsigned short f2bf(float x) {
  unsigned int b = __float_as_uint(x);
  return (unsigned short)((b + 0x7fff + ((b >> 16) & 1)) >> 16);
}
__device__ __forceinline__ float bf2f(unsigned short h) {
  return __uint_as_float(((unsigned int)h) << 16);
}

// async global->LDS, 16B per lane (dest = wave-uniform base + lane*16)
__device__ __forceinline__ void gload16(const void* g, void* l) {
  __builtin_amdgcn_global_load_lds(
      (const __attribute__((address_space(1))) void*)g,
      (__attribute__((address_space(3))) void*)l, 16, 0, 0);
}

// ---------------------------------------------------------------------------
// K0 (fused): blocks 0..511: wnorm[k] + B'' chunk layout + ws scalars.
// Blocks 512..767: A' = [bf16_hi | bf16_lo], 64 tokens/block.
__global__ void k_prep(const float* __restrict__ weight, const float* __restrict__ z,
                       float* __restrict__ out, float* __restrict__ ws) {
  __shared__ float z_s[64 * 64];                  // 16KB (A'-branch only)
  if (blockIdx.x < 512) {
    int gid = blockIdx.x * 256 + threadIdx.x;     // 0..131071
    int row = gid >> 4;                            // codebook row 0..8191
    int l16 = gid & 15;
    float4 w4 = *(const float4*)(weight + row * EMB_D + l16 * 4);
    float s = w4.x * w4.x + w4.y * w4.y + w4.z * w4.z + w4.w * w4.w;
    #pragma unroll
    for (int off = 8; off > 0; off >>= 1) s += __shfl_xor(s, off, 16);
    if (l16 == 0) ws[WS_WNORM + row] = s;

    float wv[4] = {w4.x, w4.y, w4.z, w4.w};
    us4 hi, lo;
    #pragma unroll
    for (int e = 0; e < 4; ++e) {
      unsigned short h = f2bf(wv[e]);
      hi[e] = h;
      lo[e] = f2bf(wv[e] - bf2f(h));
    }
    int d0 = l16 * 4;
    int jj = d0 & 7;                 // 0 or 4
    int lqp = (d0 >> 3) & 3;
    int sp = d0 >> 5;                // 0 or 1
    unsigned short* bp = (unsigned short*)out + B_BASE
        + (row >> 4) * 2048 + (row & 15) * 8 + lqp * 128 + jj;
    *(us4*)(bp + sp * 512) = hi;
    *(us4*)(bp + (2 + sp) * 512) = lo;

    if (gid == 0) {
      out[OFF_LOSS] = 0.f; ws[WS_LOSS] = 0.f;
      ((int*)ws)[WS_FCNT] = 0;
    }
  } else {
    const int t = threadIdx.x;
    const int pb = blockIdx.x - 512;              // 0..255
    const int b = pb >> 4;                        // batch 0..15
    const int hw0 = (pb & 15) * 64;               // hw chunk of 64
    const float* zb = z + b * 65536 + hw0;
    #pragma unroll
    for (int i = 0; i < 4; ++i) {
      int f4 = i * 256 + t;
      int d = f4 >> 4, c4 = (f4 & 15) * 4;
      *(float4*)(z_s + d * 64 + c4) = *(const float4*)(zb + d * 1024 + c4);
    }
    __syncthreads();
    const int tokl = t & 63;
    const int jq = t >> 6;                        // 0..3, wave-uniform
    int tok = b * 1024 + hw0 + tokl;
    unsigned short* ap = (unsigned short*)out + (size_t)tok * 128;
    #pragma unroll
    for (int j = jq * 4; j < jq * 4 + 4; ++j) {
      us4 hi, lo;
      #pragma unroll
      for (int e = 0; e < 4; ++e) {
        float zv = z_s[(j * 4 + e) * 64 + tokl];
        unsigned short h = f2bf(zv);
        hi[e] = h;
        lo[e] = f2bf(zv - bf2f(h));
      }
      *(us4*)(ap + j * 4) = hi;
      *(us4*)(ap + 64 + j * 4) = lo;
    }
  }
}

// ---------------------------------------------------------------------------
// K1: distance argmin on the matrix pipe (R30 structure, converged ~72.5us).
__global__ __launch_bounds__(256, 8) void k_argmin(
    const short* __restrict__ A, const short* __restrict__ B,
    const float* __restrict__ wnorm, float* __restrict__ cand) {
  __shared__ __align__(16) short wbuf[3][2048];   // 3 x 4KB chunk buffers
  __shared__ __align__(16) float wn_s[1024];      // group wnorm
  const int t = threadIdx.x;
  const int lane = t & 63;
  const int wid = __builtin_amdgcn_readfirstlane(t >> 6);  // 0..3
  const int g = blockIdx.x & 7;
  const int tok_blk = blockIdx.x >> 3;            // 0..255
  const int trow0 = tok_blk * 64 + wid * 16;
  const int lr = lane & 15, lq = lane >> 4;

  bf8 a[4];
  {
    const short* ap = A + (size_t)(trow0 + lr) * 128 + lq * 8;
    #pragma unroll
    for (int s = 0; s < 4; ++s) a[s] = *(const bf8*)(ap + s * 32);
  }

  const short* bsrc = B + (size_t)g * 64 * 2048;

  *(float4*)(wn_s + t * 4) = *(const float4*)(wnorm + g * 1024 + t * 4);
  gload16(bsrc + t * 8, &wbuf[0][0] + t * 8);
  gload16(bsrc + 2048 + t * 8, &wbuf[1][0] + t * 8);
  asm volatile("s_waitcnt vmcnt(1) lgkmcnt(0)" ::: "memory");
  __builtin_amdgcn_s_barrier();

  float d1[4], d2[4]; int i1[4];
  #pragma unroll
  for (int v = 0; v < 4; ++v) { d1[v] = 3.4e38f; d2[v] = 3.4e38f; i1[v] = 0; }

  int cur = 0, stg = 2;
  for (int c = 0; c < 64; ++c) {
    if (c + 2 < 64)
      gload16(bsrc + (c + 2) * 2048 + t * 8, &wbuf[stg][0] + t * 8);

    const short* cb = &wbuf[cur][0] + lq * 128 + lr * 8;
    float wn = wn_s[c * 16 + lr];

    bf8 b0 = *(const bf8*)(cb);
    bf8 b1 = *(const bf8*)(cb + 512);
    f32x4 acc = (f32x4)(0.f);
    acc = __builtin_amdgcn_mfma_f32_16x16x32_bf16(a[0], b0, acc, 0, 0, 0);
    acc = __builtin_amdgcn_mfma_f32_16x16x32_bf16(a[1], b1, acc, 0, 0, 0);
    acc = __builtin_amdgcn_mfma_f32_16x16x32_bf16(a[2], b0, acc, 0, 0, 0);
    acc = __builtin_amdgcn_mfma_f32_16x16x32_bf16(a[3], b1, acc, 0, 0, 0);
    bf8 b2 = *(const bf8*)(cb + 1024);
    bf8 b3 = *(const bf8*)(cb + 1536);
    acc = __builtin_amdgcn_mfma_f32_16x16x32_bf16(a[0], b2, acc, 0, 0, 0);
    acc = __builtin_amdgcn_mfma_f32_16x16x32_bf16(a[1], b3, acc, 0, 0, 0);

    const int code = g * 1024 + c * 16 + lr;
    #pragma unroll
    for (int r = 0; r < 4; ++r) {
      float d = fmaf(-2.f, acc[r], wn);
      d2[r] = __builtin_amdgcn_fmed3f(d1[r], d2[r], d);
      bool lt = d < d1[r];
      d1[r] = fminf(d1[r], d);
      i1[r] = lt ? code : i1[r];
    }

    if (c < 63) {
      if (c + 2 < 64) asm volatile("s_waitcnt vmcnt(1)" ::: "memory");
      else            asm volatile("s_waitcnt vmcnt(0)" ::: "memory");
      __builtin_amdgcn_s_barrier();
    }
    cur = (cur == 2) ? 0 : cur + 1;
    stg = (stg == 2) ? 0 : stg + 1;
  }

  #pragma unroll
  for (int m = 1; m < 16; m <<= 1) {
    #pragma unroll
    for (int v = 0; v < 4; ++v) {
      float od1 = __shfl_xor(d1[v], m, 64);
      float od2 = __shfl_xor(d2[v], m, 64);
      int   oi1 = __shfl_xor(i1[v], m, 64);
      d2[v] = fminf(fminf(d2[v], od2), fmaxf(d1[v], od1));
      bool take = (od1 < d1[v]) || (od1 == d1[v] && oi1 < i1[v]);
      d1[v] = take ? od1 : d1[v];
      i1[v] = take ? oi1 : i1[v];
    }
  }

  if (lr == 0) {                           // lanes 0,16,32,48 (lq = 0..3)
    #pragma unroll
    for (int r = 0; r < 4; ++r) {
      int token = trow0 + lq * 4 + r;
      cand[g * N_TOK + token] = d1[r];
      ((int*)cand)[CAND_I1 + g * N_TOK + token] = i1[r];
      cand[CAND_D2 + g * N_TOK + token] = d2[r];
    }
  }
}

// ---------------------------------------------------------------------------
// K2: merge GROUPS candidates (exact 2-min); packed (idx-truth) + margin
// flags; zero counts (B'' dead here; must precede k_enc).
__global__ void k_reduce(const float* __restrict__ cand, int* __restrict__ flags,
                         int* __restrict__ fcnt,
                         unsigned long long* __restrict__ packed,
                         float* __restrict__ cs) {
  int n = blockIdx.x * 256 + threadIdx.x;
  if (n < K_EMB) cs[n] = 0.f;              // counts accumulator zero
  const int* ci = (const int*)cand + CAND_I1;
  float D1 = cand[n]; int I1 = ci[n]; float D2 = cand[CAND_D2 + n];
  #pragma unroll
  for (int g = 1; g < GROUPS; ++g) {
    float d = cand[g * N_TOK + n];
    int   i = ci[g * N_TOK + n];
    float dd = cand[CAND_D2 + g * N_TOK + n];
    D2 = fminf(fminf(D2, dd), fmaxf(D1, d));
    bool take = (d < D1) || (d == D1 && i < I1);
    D1 = take ? d : D1; I1 = take ? i : I1;
  }
  if (D2 - D1 < MARGIN) {
    packed[n] = ~0ull;                     // refine will atomicMin exact vals
    int p = atomicAdd(fcnt, 1);
    flags[p] = n;
  } else {
    unsigned int bits = __float_as_uint(D1);
    unsigned int u = (bits & 0x80000000u) ? ~bits : (bits | 0x80000000u);
    packed[n] = ((unsigned long long)u << 32) | (unsigned int)I1;
  }
}

// ---------------------------------------------------------------------------
// K2b: exact fp32 refine, 16-lane-group structure (R34). Work item w =
// (flag f, 1024-code subrange); wave handles 256 codes in 64 iters of 4:
// group lg (16 lanes) owns code k+lg; lane holds dims ld*4..ld*4+3 (float4
// from weight, 1KB/wave-iter coalesced); 4-level shfl reduce within 16
// lanes; per-group strict < (codes ascend within group); cross-group
// butterfly (xor 16,32) with index tie-break == numpy first-min.
__global__ void k_refine(const float* __restrict__ z, const float* __restrict__ weight,
                         const float* __restrict__ wnorm, const int* __restrict__ flags,
                         const int* __restrict__ fcnt,
                         unsigned long long* __restrict__ packed) {
  const int cnt = *fcnt;
  const int lane = threadIdx.x & 63;
  const int wv = threadIdx.x >> 6;
  const int lg = lane >> 4;                // group 0..3
  const int ld = lane & 15;                // lane-in-group
  for (int w = blockIdx.x; w < cnt * 8; w += gridDim.x) {
    const int f = w >> 3, sub = w & 7;
    const int n = flags[f];
    const int b = n >> 10, hw = n & 1023;
    const float* zb = z + b * 65536 + hw;
    float4 zf;
    zf.x = zb[(ld * 4 + 0) * 1024];
    zf.y = zb[(ld * 4 + 1) * 1024];
    zf.z = zb[(ld * 4 + 2) * 1024];
    zf.w = zb[(ld * 4 + 3) * 1024];
    float bd = 3.4e38f; int bi = 0;
    const int k0 = sub * 1024 + wv * 256;
    #pragma unroll 4
    for (int i = 0; i < 256; i += 4) {
      const int k = k0 + i + lg;           // this group's code
      const float4 wf = *(const float4*)(weight + k * EMB_D + ld * 4);
      float p = zf.x * wf.x;
      p = fmaf(zf.y, wf.y, p);
      p = fmaf(zf.z, wf.z, p);
      p = fmaf(zf.w, wf.w, p);
      #pragma unroll
      for (int off = 8; off > 0; off >>= 1) p += __shfl_xor(p, off, 16);
      float dist = fmaf(-2.f, p, wnorm[k]);
      if (dist < bd) { bd = dist; bi = k; }   // codes ascend within group
    }
    // cross-group merge (all 16 lanes of a group hold identical bd/bi)
    #pragma unroll
    for (int m = 16; m < 64; m <<= 1) {
      float od = __shfl_xor(bd, m, 64);
      int   oi = __shfl_xor(bi, m, 64);
      bool take = (od < bd) || (od == bd && oi < bi);
      bd = take ? od : bd;
      bi = take ? oi : bi;
    }
    if (lane == 0) {
      unsigned int bits = __float_as_uint(bd);
      unsigned int u = (bits & 0x80000000u) ? ~bits : (bits | 0x80000000u);
      atomicMin(packed + n, ((unsigned long long)u << 32) | (unsigned int)bi);
    }
  }
}

// ---------------------------------------------------------------------------
// K2c: idx + enc counts from packed (post-refine truth).
__global__ void k_enc(const unsigned long long* __restrict__ packed,
                      int* __restrict__ idx, float* __restrict__ cnt) {
  int n = blockIdx.x * 256 + threadIdx.x;
  int k = (int)(packed[n] & 0xffffffffull);
  idx[n] = k;
  atomicAdd(cnt + k, 1.0f);
}

// ---------------------------------------------------------------------------
// K2e: exclusive prefix-sum of counts -> offs + cursors; also nsum
// closed-form: 0.99*sum(cluster_in) + 0.01*N_TOK (sum enc == N_TOK exact).
__global__ void k_scan(const float* __restrict__ cnt,
                       const float* __restrict__ cluster_in,
                       int* __restrict__ offs, int* __restrict__ curs,
                       float* __restrict__ ws) {
  __shared__ int part[256];
  __shared__ float fpart[256];
  const int t = threadIdx.x;
  const int base = t * 32;
  int local[32];
  int s = 0;
  #pragma unroll
  for (int i = 0; i < 32; ++i) { local[i] = s; s += (int)cnt[base + i]; }
  part[t] = s;
  float csl = 0.f;
  #pragma unroll
  for (int i = 0; i < 32; ++i) csl += cluster_in[base + i];
  fpart[t] = csl;
  __syncthreads();
  if (t == 0) {
    int run = 0;
    for (int i = 0; i < 256; ++i) { int v = part[i]; part[i] = run; run += v; }
    float cs2 = 0.f;
    for (int i = 0; i < 256; ++i) cs2 += fpart[i];
    ws[WS_NSUM] = 0.99f * cs2 + 0.01f * (float)N_TOK;
  }
  __syncthreads();
  const int p = part[t];
  #pragma unroll
  for (int i = 0; i < 32; ++i) {
    offs[base + i] = p + local[i];
    curs[base + i] = p + local[i];
  }
}

// ---------------------------------------------------------------------------
// K2f: scatter token ids grouped by code (16K atomics over 8K cursors).
__global__ void k_scatter(const int* __restrict__ idx, int* __restrict__ curs,
                          int* __restrict__ toklist) {
  int n = blockIdx.x * 256 + threadIdx.x;
  int k = idx[n];
  int pos = atomicAdd(curs + k, 1);
  toklist[pos] = n;
}

// ---------------------------------------------------------------------------
// K2g: segmented embed_sum, BLOCK per code: wave w takes tokens i%4==w;
// per token ONE coalesced 256B wave-load of the A' row; shfl_xor(32) folds
// hi+lo; LDS folds 4 waves; store 256B. No atomics. Overwrites EA fully.
__global__ void k_embed(const unsigned short* __restrict__ A,
                        const float* __restrict__ cnt,
                        const int* __restrict__ offs,
                        const int* __restrict__ toklist,
                        float* __restrict__ embed) {
  __shared__ float sh[4][EMB_D];
  const int t = threadIdx.x;
  const int lane = t & 63;
  const int w = t >> 6;                    // wave 0..3
  const int k = blockIdx.x;
  const int m = (int)cnt[k];
  const int off = offs[k];

  float sA = 0.f, sB = 0.f;                // pair partials for this lane
  #pragma unroll 2
  for (int i = w; i < m; i += 4) {
    int tok = toklist[off + i];            // wave-uniform -> s_load
    unsigned v = *(const unsigned*)(A + (size_t)tok * 128 + 2 * lane);
    sA += bf2f((unsigned short)(v & 0xffffu));
    sB += bf2f((unsigned short)(v >> 16));
  }
  sA += __shfl_xor(sA, 32, 64);
  sB += __shfl_xor(sB, 32, 64);
  if (lane < 32) {
    sh[w][2 * lane] = sA;
    sh[w][2 * lane + 1] = sB;
  }
  __syncthreads();
  if (t < EMB_D)
    embed[k * EMB_D + t] = sh[0][t] + sh[1][t] + sh[2][t] + sh[3][t];
}

// ---------------------------------------------------------------------------
// K3: z_q gather + straight-through output + loss partials. x4 vectorized.
__global__ void k_quant(const float* __restrict__ z, const float* __restrict__ weight,
                        const int* __restrict__ idx, float* __restrict__ out,
                        float* __restrict__ ws) {
  int e0 = (blockIdx.x * 256 + threadIdx.x) * 4;
  int c = (e0 >> 10) & 63;
  int n0 = ((e0 >> 16) << 10) | (e0 & 1023);
  float4 zv = *(const float4*)(z + e0);
  int4 kk = *(const int4*)(idx + n0);
  float4 q;
  q.x = weight[kk.x * EMB_D + c];
  q.y = weight[kk.y * EMB_D + c];
  q.z = weight[kk.z * EMB_D + c];
  q.w = weight[kk.w * EMB_D + c];
  *(float4*)(out + e0) = q;               // straight-through value z+(q-z)=q
  float dx = q.x - zv.x, dy = q.y - zv.y, dz = q.z - zv.z, dw = q.w - zv.w;
  float lsum = dx * dx + dy * dy + dz * dz + dw * dw;
  #pragma unroll
  for (int off = 32; off > 0; off >>= 1) lsum += __shfl_xor(lsum, off, 64);
  __shared__ float red[4];
  int lane = threadIdx.x & 63, wv = threadIdx.x >> 6;
  if (lane == 0) red[wv] = lsum;
  __syncthreads();
  if (threadIdx.x == 0)
    atomicAdd(ws + WS_LOSS, red[0] + red[1] + red[2] + red[3]);
}

// ---------------------------------------------------------------------------
// K5 (fused cluster+final, x4): 4 consecutive e share one k. ncs from raw
// counts; CS written once per k by the (e0&63)==0 thread AFTER block-local
// cnt reads (block owns whole k-groups -> race-free). Loss finalized here.
__global__ void k_final(const float* __restrict__ cluster_in,
                        const float* __restrict__ embed_avg,
                        float* __restrict__ out, const float* __restrict__ ws) {
  int e0 = (blockIdx.x * 256 + threadIdx.x) * 4;   // < 524288
  int k = e0 >> 6;
  float cntk = out[OFF_CS + k];             // raw count
  float ncs = cluster_in[k] * 0.99f + 0.01f * cntk;
  float nsum = ws[WS_NSUM];
  float sm = (ncs + 1e-5f) / (nsum + K_EMB * 1e-5f) * nsum;
  float inv_sm = 1.0f / sm;
  float4 eav = *(const float4*)(embed_avg + e0);
  float4 acc = *(const float4*)(out + OFF_EA + e0);
  float4 ea;
  ea.x = eav.x * 0.99f + 0.01f * acc.x;
  ea.y = eav.y * 0.99f + 0.01f * acc.y;
  ea.z = eav.z * 0.99f + 0.01f * acc.z;
  ea.w = eav.w * 0.99f + 0.01f * acc.w;
  __syncthreads();                          // all cnt reads in block done
  if ((e0 & 63) == 0) out[OFF_CS + k] = ncs;
  *(float4*)(out + OFF_EA + e0) = ea;
  float4 w4;
  w4.x = ea.x * inv_sm; w4.y = ea.y * inv_sm;
  w4.z = ea.z * inv_sm; w4.w = ea.w * inv_sm;
  *(float4*)(out + OFF_W + e0) = w4;
  if (e0 == 0)
    out[OFF_LOSS] = 0.25f * ws[WS_LOSS] * (1.0f / 1048576.0f);
}

// ---------------------------------------------------------------------------
extern "C" void kernel_launch(void* const* d_in, const int* in_sizes, int n_in,
                              void* d_out, int out_size, void* d_ws, size_t ws_size,
                              hipStream_t stream) {
  const float* z = (const float*)d_in[0];
  const float* weight = (const float*)d_in[1];
  const float* cluster = (const float*)d_in[2];
  const float* embed_avg = (const float*)d_in[3];
  float* out = (float*)d_out;
  float* ws = (float*)d_ws;
  float* wnorm = ws + WS_WNORM;
  int* idx = (int*)(ws + WS_IDX);
  int* fcnt = (int*)ws + WS_FCNT;
  const short* Ap = (const short*)out;                     // A' in z_q region
  const short* Bp = (const short*)((unsigned short*)out + B_BASE);
  float* cand = out + OFF_EA;
  unsigned long long* packed = (unsigned long long*)(out + PK_BASE);
  int* flags = (int*)out + SCR_FLAGS;                      // dead-B'' scratch
  int* toklist = (int*)out + SCR_TOK;
  int* offs = (int*)out + SCR_OFFS;
  int* curs = (int*)out + SCR_CURS;

  hipLaunchKernelGGL(k_prep, dim3(768), dim3(256), 0, stream, weight, z, out, ws);
  hipLaunchKernelGGL(k_argmin, dim3(2048), dim3(256), 0, stream,
                     Ap, Bp, wnorm, cand);
  hipLaunchKernelGGL(k_reduce, dim3(N_TOK / 256), dim3(256), 0, stream,
                     cand, flags, fcnt, packed, out + OFF_CS);
  hipLaunchKernelGGL(k_refine, dim3(2048), dim3(256), 0, stream,
                     z, weight, wnorm, flags, fcnt, packed);
  hipLaunchKernelGGL(k_enc, dim3(N_TOK / 256), dim3(256), 0, stream,
                     packed, idx, out + OFF_CS);
  hipLaunchKernelGGL(k_scan, dim3(1), dim3(256), 0, stream,
                     out + OFF_CS, cluster, offs, curs, ws);
  hipLaunchKernelGGL(k_scatter, dim3(N_TOK / 256), dim3(256), 0, stream,
                     idx, curs, toklist);
  hipLaunchKernelGGL(k_embed, dim3(K_EMB), dim3(256), 0, stream,
                     (const unsigned short*)out, out + OFF_CS, offs, toklist,
                     out + OFF_EA);
  hipLaunchKernelGGL(k_quant, dim3(1024), dim3(256), 0, stream,
                     z, weight, idx, out, ws);
  hipLaunchKernelGGL(k_final, dim3(512), dim3(256), 0, stream,
                     cluster, embed_avg, out, ws);
}

// Round 18
// 188.077 us; speedup vs baseline: 1.2773x; 1.0346x over previous
//
#include <hip/hip_runtime.h>

// EMA Vector-Quantizer for MI355X (gfx950).
// N=16384 tokens, D=64, K=8192.
// R17-R19: fp32 VALU GEMM plateau 203us. R20-R23: bf16 hi/lo split GEMM on
// matrix pipe + exact-margin fp32 refine. R24: wave-per-code refine.
// R25: atomic-free embed. R26/R29/R30: argmin ~71-73us (occupancy doubling
// = null -> not wave-starved). R31: embed block-per-code. R32 (failed):
// coop mega-kernel, per-XCD L2 staleness (G16). R33: A'-prep re-grid.
// R34: 16-lane-group refine (the hidden ~50-70us) -> 194.6us CONFIRMED.
// R35 (this):
//  - k_argmin: barrier halving 64->32 (R30 ruled out occupancy; suspect =
//    per-chunk block-convergence). Stage 8KB PAIRS (2 sub-chunks, 2 gloads
//    per thread), triple-buffered, vmcnt(2) counted (vmcnt(0) at c=61),
//    barrier every 2nd sub-chunk. LDS 28KB -> 5 blocks/CU, LB(256,5).
//    Falsifier: argmin >=72 -> barrier theory dead, revert next round.
//  - loss via distance identity: sum(q-z)^2 = sum z^2 + sum_n d_n (d_n in
//    packed: exact for refined, fp32-GEMM approx else; loss err ~4e-6).
//    z^2 block partials in prep (slots, race-free), summed in scan; d
//    unpacked+summed in enc. Breaks quant->loss->final chain ->
//    k_quant + k_final FUSE into k_quant_final (1536 blocks, role split).
//    10 -> 9 launches. WS_LOSS zeroed in reduce (pre-enc).
// Scratch liveness (out buffer):
//   A' bf16[16384][128] @ 0      : prep -> k_embed, then z_q (quant role)
//   B'' @ float 1056768 (2MB)    : prep -> k_argmin, then int scratch
//     FLAGS@1056768 TOK@1073152 OFFS@1089536 CURS@1097736 (all < CS;
//     dead before k_quant_final's W writes)
//   cand [EA, +393216) / packed @ PK_BASE : packed read by enc/scatter;
//     dead before k_embed overwrites EA
//   counts @ OFF_CS: zeroed in k_reduce -> k_enc -> scan/embed/final role
// Predicted: argmin ~64-69 (occ counter ~40% expected), total ~178-188.

#define N_TOK 16384
#define K_EMB 8192
#define EMB_D 64
#define GROUPS 8

typedef short bf8 __attribute__((ext_vector_type(8)));
typedef float f32x4 __attribute__((ext_vector_type(4)));
typedef unsigned short us4 __attribute__((ext_vector_type(4)));

// d_out flat layout (float32), reference return order:
// z_q (1048576) | loss | new_weight (524288) | new_cluster_size (8192) | new_embed_avg (524288)
#define OFF_LOSS 1048576
#define OFF_W    1048577
#define OFF_CS   1572865
#define OFF_EA   1581057

// scratch offsets
#define B_BASE   2113536   // ushort index into out = byte 4227072 (16B aligned)
#define CAND_I1  131072    // within EA-based cand area (floats/ints)
#define CAND_D2  262144
#define PK_BASE  (OFF_EA + 393217)  // even float idx -> 8B-aligned u64[16384]

// int-indexed scratch in dead-B'' (W region, consumed before k_quant_final)
#define SCR_FLAGS 1056768
#define SCR_TOK   1073152
#define SCR_OFFS  1089536
#define SCR_CURS  1097736

#define MARGIN 0.01f

// ws float offsets
#define WS_NSUM  0
#define WS_LOSS  1
#define WS_FCNT  2        // int
#define WS_ZSQ   3        // sum z^2 (written by scan)
#define WS_WNORM 16
#define WS_IDX   (WS_WNORM + K_EMB)       // int idx[16384]
#define WS_ZSQ_P (WS_IDX + N_TOK)         // 256 per-block z^2 partials

__device__ __forceinline__ unsigned short f2bf(float x) {
  unsigned int b = __float_as_uint(x);
  return (unsigned short)((b + 0x7fff + ((b >> 16) & 1)) >> 16);
}
__device__ __forceinline__ float bf2f(unsigned short h) {
  return __uint_as_float(((unsigned int)h) << 16);
}

// async global->LDS, 16B per lane (dest = wave-uniform base + lane*16)
__device__ __forceinline__ void gload16(const void* g, void* l) {
  __builtin_amdgcn_global_load_lds(
      (const __attribute__((address_space(1))) void*)g,
      (__attribute__((address_space(3))) void*)l, 16, 0, 0);
}

// ---------------------------------------------------------------------------
// K0 (fused): blocks 0..511: wnorm[k] + B'' chunk layout + fcnt zero.
// Blocks 512..767: A' = [bf16_hi | bf16_lo], 64 tokens/block + z^2 partial.
__global__ void k_prep(const float* __restrict__ weight, const float* __restrict__ z,
                       float* __restrict__ out, float* __restrict__ ws) {
  __shared__ float z_s[64 * 64];                  // 16KB (A'-branch only)
  __shared__ float zred[4];
  if (blockIdx.x < 512) {
    int gid = blockIdx.x * 256 + threadIdx.x;     // 0..131071
    int row = gid >> 4;                            // codebook row 0..8191
    int l16 = gid & 15;
    float4 w4 = *(const float4*)(weight + row * EMB_D + l16 * 4);
    float s = w4.x * w4.x + w4.y * w4.y + w4.z * w4.z + w4.w * w4.w;
    #pragma unroll
    for (int off = 8; off > 0; off >>= 1) s += __shfl_xor(s, off, 16);
    if (l16 == 0) ws[WS_WNORM + row] = s;

    float wv[4] = {w4.x, w4.y, w4.z, w4.w};
    us4 hi, lo;
    #pragma unroll
    for (int e = 0; e < 4; ++e) {
      unsigned short h = f2bf(wv[e]);
      hi[e] = h;
      lo[e] = f2bf(wv[e] - bf2f(h));
    }
    int d0 = l16 * 4;
    int jj = d0 & 7;                 // 0 or 4
    int lqp = (d0 >> 3) & 3;
    int sp = d0 >> 5;                // 0 or 1
    unsigned short* bp = (unsigned short*)out + B_BASE
        + (row >> 4) * 2048 + (row & 15) * 8 + lqp * 128 + jj;
    *(us4*)(bp + sp * 512) = hi;
    *(us4*)(bp + (2 + sp) * 512) = lo;

    if (gid == 0) ((int*)ws)[WS_FCNT] = 0;
  } else {
    const int t = threadIdx.x;
    const int pb = blockIdx.x - 512;              // 0..255
    const int b = pb >> 4;                        // batch 0..15
    const int hw0 = (pb & 15) * 64;               // hw chunk of 64
    const float* zb = z + b * 65536 + hw0;
    float zsq = 0.f;
    #pragma unroll
    for (int i = 0; i < 4; ++i) {
      int f4 = i * 256 + t;
      int d = f4 >> 4, c4 = (f4 & 15) * 4;
      float4 v = *(const float4*)(zb + d * 1024 + c4);
      zsq += v.x * v.x + v.y * v.y + v.z * v.z + v.w * v.w;
      *(float4*)(z_s + d * 64 + c4) = v;
    }
    __syncthreads();
    const int tokl = t & 63;
    const int jq = t >> 6;                        // 0..3, wave-uniform
    int tok = b * 1024 + hw0 + tokl;
    unsigned short* ap = (unsigned short*)out + (size_t)tok * 128;
    #pragma unroll
    for (int j = jq * 4; j < jq * 4 + 4; ++j) {
      us4 hi, lo;
      #pragma unroll
      for (int e = 0; e < 4; ++e) {
        float zv = z_s[(j * 4 + e) * 64 + tokl];
        unsigned short h = f2bf(zv);
        hi[e] = h;
        lo[e] = f2bf(zv - bf2f(h));
      }
      *(us4*)(ap + j * 4) = hi;
      *(us4*)(ap + 64 + j * 4) = lo;
    }
    // z^2 partial -> slot pb (race-free: one writer per slot)
    #pragma unroll
    for (int off = 32; off > 0; off >>= 1) zsq += __shfl_xor(zsq, off, 64);
    if ((t & 63) == 0) zred[t >> 6] = zsq;
    __syncthreads();
    if (t == 0) ws[WS_ZSQ_P + pb] = zred[0] + zred[1] + zred[2] + zred[3];
  }
}

// ---------------------------------------------------------------------------
// K1: distance argmin on the matrix pipe. R35: 8KB pair staging (2 sub-
// chunks per stage), triple-buffered, barrier every 2nd sub-chunk (32
// barriers vs 64). vmcnt ledger: stages=2 loads; prologue P0,P1 +
// vmcnt(2) -> P0; at odd c: vmcnt(2) -> P(c>>1 +1) landed (vmcnt(0) at
// c=61 since nothing staged after P31). LDS 24+4KB -> 5 blocks/CU.
__global__ __launch_bounds__(256, 5) void k_argmin(
    const short* __restrict__ A, const short* __restrict__ B,
    const float* __restrict__ wnorm, float* __restrict__ cand) {
  __shared__ __align__(16) short wbuf[3][4096];   // 3 x 8KB pair buffers
  __shared__ __align__(16) float wn_s[1024];      // group wnorm
  const int t = threadIdx.x;
  const int lane = t & 63;
  const int wid = __builtin_amdgcn_readfirstlane(t >> 6);  // 0..3
  const int g = blockIdx.x & 7;
  const int tok_blk = blockIdx.x >> 3;            // 0..255
  const int trow0 = tok_blk * 64 + wid * 16;
  const int lr = lane & 15, lq = lane >> 4;

  bf8 a[4];
  {
    const short* ap = A + (size_t)(trow0 + lr) * 128 + lq * 8;
    #pragma unroll
    for (int s = 0; s < 4; ++s) a[s] = *(const bf8*)(ap + s * 32);
  }

  const short* bsrc = B + (size_t)g * 64 * 2048;

  *(float4*)(wn_s + t * 4) = *(const float4*)(wnorm + g * 1024 + t * 4);
  // prologue: stage pairs 0,1 (each = 2 gloads of 4KB)
  gload16(bsrc + t * 8, &wbuf[0][0] + t * 8);
  gload16(bsrc + 2048 + t * 8, &wbuf[0][0] + 2048 + t * 8);
  gload16(bsrc + 4096 + t * 8, &wbuf[1][0] + t * 8);
  gload16(bsrc + 6144 + t * 8, &wbuf[1][0] + 2048 + t * 8);
  asm volatile("s_waitcnt vmcnt(2) lgkmcnt(0)" ::: "memory");
  __builtin_amdgcn_s_barrier();

  float d1[4], d2[4]; int i1[4];
  #pragma unroll
  for (int v = 0; v < 4; ++v) { d1[v] = 3.4e38f; d2[v] = 3.4e38f; i1[v] = 0; }

  for (int c = 0; c < 64; ++c) {
    const int p = c >> 1, half = c & 1;
    if (half == 0) {
      const int ps = p + 2;                        // stage pair ps
      if (ps < 32) {
        short* db = &wbuf[ps % 3][0];
        gload16(bsrc + ps * 4096 + t * 8, db + t * 8);
        gload16(bsrc + ps * 4096 + 2048 + t * 8, db + 2048 + t * 8);
      }
    }

    const short* cb = &wbuf[p % 3][0] + half * 2048 + lq * 128 + lr * 8;
    float wn = wn_s[c * 16 + lr];

    bf8 b0 = *(const bf8*)(cb);
    bf8 b1 = *(const bf8*)(cb + 512);
    f32x4 acc = (f32x4)(0.f);
    acc = __builtin_amdgcn_mfma_f32_16x16x32_bf16(a[0], b0, acc, 0, 0, 0);
    acc = __builtin_amdgcn_mfma_f32_16x16x32_bf16(a[1], b1, acc, 0, 0, 0);
    acc = __builtin_amdgcn_mfma_f32_16x16x32_bf16(a[2], b0, acc, 0, 0, 0);
    acc = __builtin_amdgcn_mfma_f32_16x16x32_bf16(a[3], b1, acc, 0, 0, 0);
    bf8 b2 = *(const bf8*)(cb + 1024);
    bf8 b3 = *(const bf8*)(cb + 1536);
    acc = __builtin_amdgcn_mfma_f32_16x16x32_bf16(a[0], b2, acc, 0, 0, 0);
    acc = __builtin_amdgcn_mfma_f32_16x16x32_bf16(a[1], b3, acc, 0, 0, 0);

    const int code = g * 1024 + c * 16 + lr;
    #pragma unroll
    for (int r = 0; r < 4; ++r) {
      float d = fmaf(-2.f, acc[r], wn);
      d2[r] = __builtin_amdgcn_fmed3f(d1[r], d2[r], d);
      bool lt = d < d1[r];
      d1[r] = fminf(d1[r], d);
      i1[r] = lt ? code : i1[r];
    }

    if (half == 1 && c < 63) {
      if (c == 61) asm volatile("s_waitcnt vmcnt(0)" ::: "memory");
      else         asm volatile("s_waitcnt vmcnt(2)" ::: "memory");
      __builtin_amdgcn_s_barrier();
    }
  }

  #pragma unroll
  for (int m = 1; m < 16; m <<= 1) {
    #pragma unroll
    for (int v = 0; v < 4; ++v) {
      float od1 = __shfl_xor(d1[v], m, 64);
      float od2 = __shfl_xor(d2[v], m, 64);
      int   oi1 = __shfl_xor(i1[v], m, 64);
      d2[v] = fminf(fminf(d2[v], od2), fmaxf(d1[v], od1));
      bool take = (od1 < d1[v]) || (od1 == d1[v] && oi1 < i1[v]);
      d1[v] = take ? od1 : d1[v];
      i1[v] = take ? oi1 : i1[v];
    }
  }

  if (lr == 0) {                           // lanes 0,16,32,48 (lq = 0..3)
    #pragma unroll
    for (int r = 0; r < 4; ++r) {
      int token = trow0 + lq * 4 + r;
      cand[g * N_TOK + token] = d1[r];
      ((int*)cand)[CAND_I1 + g * N_TOK + token] = i1[r];
      cand[CAND_D2 + g * N_TOK + token] = d2[r];
    }
  }
}

// ---------------------------------------------------------------------------
// K2: merge GROUPS candidates (exact 2-min); packed (idx+dist truth) +
// margin flags; zero counts + WS_LOSS (pre-enc; B'' dead here).
__global__ void k_reduce(const float* __restrict__ cand, int* __restrict__ flags,
                         int* __restrict__ fcnt,
                         unsigned long long* __restrict__ packed,
                         float* __restrict__ cs, float* __restrict__ ws) {
  int n = blockIdx.x * 256 + threadIdx.x;
  if (n < K_EMB) cs[n] = 0.f;              // counts accumulator zero
  if (n == 0) ws[WS_LOSS] = 0.f;
  const int* ci = (const int*)cand + CAND_I1;
  float D1 = cand[n]; int I1 = ci[n]; float D2 = cand[CAND_D2 + n];
  #pragma unroll
  for (int g = 1; g < GROUPS; ++g) {
    float d = cand[g * N_TOK + n];
    int   i = ci[g * N_TOK + n];
    float dd = cand[CAND_D2 + g * N_TOK + n];
    D2 = fminf(fminf(D2, dd), fmaxf(D1, d));
    bool take = (d < D1) || (d == D1 && i < I1);
    D1 = take ? d : D1; I1 = take ? i : I1;
  }
  if (D2 - D1 < MARGIN) {
    packed[n] = ~0ull;                     // refine will atomicMin exact vals
    int p = atomicAdd(fcnt, 1);
    flags[p] = n;
  } else {
    unsigned int bits = __float_as_uint(D1);
    unsigned int u = (bits & 0x80000000u) ? ~bits : (bits | 0x80000000u);
    packed[n] = ((unsigned long long)u << 32) | (unsigned int)I1;
  }
}

// ---------------------------------------------------------------------------
// K2b: exact fp32 refine, 16-lane-group structure (R34).
__global__ void k_refine(const float* __restrict__ z, const float* __restrict__ weight,
                         const float* __restrict__ wnorm, const int* __restrict__ flags,
                         const int* __restrict__ fcnt,
                         unsigned long long* __restrict__ packed) {
  const int cnt = *fcnt;
  const int lane = threadIdx.x & 63;
  const int wv = threadIdx.x >> 6;
  const int lg = lane >> 4;                // group 0..3
  const int ld = lane & 15;                // lane-in-group
  for (int w = blockIdx.x; w < cnt * 8; w += gridDim.x) {
    const int f = w >> 3, sub = w & 7;
    const int n = flags[f];
    const int b = n >> 10, hw = n & 1023;
    const float* zb = z + b * 65536 + hw;
    float4 zf;
    zf.x = zb[(ld * 4 + 0) * 1024];
    zf.y = zb[(ld * 4 + 1) * 1024];
    zf.z = zb[(ld * 4 + 2) * 1024];
    zf.w = zb[(ld * 4 + 3) * 1024];
    float bd = 3.4e38f; int bi = 0;
    const int k0 = sub * 1024 + wv * 256;
    #pragma unroll 4
    for (int i = 0; i < 256; i += 4) {
      const int k = k0 + i + lg;           // this group's code
      const float4 wf = *(const float4*)(weight + k * EMB_D + ld * 4);
      float p = zf.x * wf.x;
      p = fmaf(zf.y, wf.y, p);
      p = fmaf(zf.z, wf.z, p);
      p = fmaf(zf.w, wf.w, p);
      #pragma unroll
      for (int off = 8; off > 0; off >>= 1) p += __shfl_xor(p, off, 16);
      float dist = fmaf(-2.f, p, wnorm[k]);
      if (dist < bd) { bd = dist; bi = k; }   // codes ascend within group
    }
    #pragma unroll
    for (int m = 16; m < 64; m <<= 1) {
      float od = __shfl_xor(bd, m, 64);
      int   oi = __shfl_xor(bi, m, 64);
      bool take = (od < bd) || (od == bd && oi < bi);
      bd = take ? od : bd;
      bi = take ? oi : bi;
    }
    if (lane == 0) {
      unsigned int bits = __float_as_uint(bd);
      unsigned int u = (bits & 0x80000000u) ? ~bits : (bits | 0x80000000u);
      atomicMin(packed + n, ((unsigned long long)u << 32) | (unsigned int)bi);
    }
  }
}

// ---------------------------------------------------------------------------
// K2c: idx + enc counts + loss partials (sum d_n unpacked from packed).
__global__ void k_enc(const unsigned long long* __restrict__ packed,
                      int* __restrict__ idx, float* __restrict__ cnt,
                      float* __restrict__ ws) {
  int n = blockIdx.x * 256 + threadIdx.x;
  unsigned long long pk = packed[n];
  int k = (int)(pk & 0xffffffffull);
  idx[n] = k;
  atomicAdd(cnt + k, 1.0f);
  unsigned int u = (unsigned int)(pk >> 32);
  unsigned int bits = (u & 0x80000000u) ? (u & 0x7fffffffu) : ~u;
  float d = __uint_as_float(bits);
  #pragma unroll
  for (int off = 32; off > 0; off >>= 1) d += __shfl_xor(d, off, 64);
  __shared__ float red[4];
  int lane = threadIdx.x & 63, wv = threadIdx.x >> 6;
  if (lane == 0) red[wv] = d;
  __syncthreads();
  if (threadIdx.x == 0)
    atomicAdd(ws + WS_LOSS, red[0] + red[1] + red[2] + red[3]);
}

// ---------------------------------------------------------------------------
// K2e: exclusive prefix-sum of counts -> offs + cursors; nsum closed-form;
// z^2 partial total.
__global__ void k_scan(const float* __restrict__ cnt,
                       const float* __restrict__ cluster_in,
                       int* __restrict__ offs, int* __restrict__ curs,
                       float* __restrict__ ws) {
  __shared__ int part[256];
  __shared__ float fpart[256];
  __shared__ float zp[256];
  const int t = threadIdx.x;
  const int base = t * 32;
  int local[32];
  int s = 0;
  #pragma unroll
  for (int i = 0; i < 32; ++i) { local[i] = s; s += (int)cnt[base + i]; }
  part[t] = s;
  float csl = 0.f;
  #pragma unroll
  for (int i = 0; i < 32; ++i) csl += cluster_in[base + i];
  fpart[t] = csl;
  zp[t] = ws[WS_ZSQ_P + t];
  __syncthreads();
  if (t == 0) {
    int run = 0;
    for (int i = 0; i < 256; ++i) { int v = part[i]; part[i] = run; run += v; }
    float cs2 = 0.f, zs = 0.f;
    for (int i = 0; i < 256; ++i) { cs2 += fpart[i]; zs += zp[i]; }
    ws[WS_NSUM] = 0.99f * cs2 + 0.01f * (float)N_TOK;
    ws[WS_ZSQ] = zs;
  }
  __syncthreads();
  const int p = part[t];
  #pragma unroll
  for (int i = 0; i < 32; ++i) {
    offs[base + i] = p + local[i];
    curs[base + i] = p + local[i];
  }
}

// ---------------------------------------------------------------------------
// K2f: scatter token ids grouped by code (16K atomics over 8K cursors).
__global__ void k_scatter(const int* __restrict__ idx, int* __restrict__ curs,
                          int* __restrict__ toklist) {
  int n = blockIdx.x * 256 + threadIdx.x;
  int k = idx[n];
  int pos = atomicAdd(curs + k, 1);
  toklist[pos] = n;
}

// ---------------------------------------------------------------------------
// K2g: segmented embed_sum, BLOCK per code (R31 structure).
__global__ void k_embed(const unsigned short* __restrict__ A,
                        const float* __restrict__ cnt,
                        const int* __restrict__ offs,
                        const int* __restrict__ toklist,
                        float* __restrict__ embed) {
  __shared__ float sh[4][EMB_D];
  const int t = threadIdx.x;
  const int lane = t & 63;
  const int w = t >> 6;                    // wave 0..3
  const int k = blockIdx.x;
  const int m = (int)cnt[k];
  const int off = offs[k];

  float sA = 0.f, sB = 0.f;                // pair partials for this lane
  #pragma unroll 2
  for (int i = w; i < m; i += 4) {
    int tok = toklist[off + i];            // wave-uniform -> s_load
    unsigned v = *(const unsigned*)(A + (size_t)tok * 128 + 2 * lane);
    sA += bf2f((unsigned short)(v & 0xffffu));
    sB += bf2f((unsigned short)(v >> 16));
  }
  sA += __shfl_xor(sA, 32, 64);
  sB += __shfl_xor(sB, 32, 64);
  if (lane < 32) {
    sh[w][2 * lane] = sA;
    sh[w][2 * lane + 1] = sB;
  }
  __syncthreads();
  if (t < EMB_D)
    embed[k * EMB_D + t] = sh[0][t] + sh[1][t] + sh[2][t] + sh[3][t];
}

// ---------------------------------------------------------------------------
// K3 (fused quant+final): blocks 0..1023 = quant role (z_q gather, x4; no
// loss -- loss comes from the distance identity). Blocks 1024..1535 =
// final role (cluster+final x4 + loss finalize from WS_ZSQ + WS_LOSS).
// Both roles depend only on stages <= embed; outputs disjoint.
__global__ void k_quant_final(const float* __restrict__ z,
                              const float* __restrict__ weight,
                              const float* __restrict__ cluster_in,
                              const float* __restrict__ embed_avg,
                              const int* __restrict__ idx,
                              float* __restrict__ out,
                              const float* __restrict__ ws) {
  if (blockIdx.x < 1024) {
    int e0 = (blockIdx.x * 256 + threadIdx.x) * 4;
    int c = (e0 >> 10) & 63;
    int n0 = ((e0 >> 16) << 10) | (e0 & 1023);
    int4 kk = *(const int4*)(idx + n0);
    float4 q;
    q.x = weight[kk.x * EMB_D + c];
    q.y = weight[kk.y * EMB_D + c];
    q.z = weight[kk.z * EMB_D + c];
    q.w = weight[kk.w * EMB_D + c];
    *(float4*)(out + e0) = q;             // straight-through value z+(q-z)=q
  } else {
    int e0 = ((blockIdx.x - 1024) * 256 + threadIdx.x) * 4;   // < 524288
    int k = e0 >> 6;
    float cntk = out[OFF_CS + k];           // raw count
    float ncs = cluster_in[k] * 0.99f + 0.01f * cntk;
    float nsum = ws[WS_NSUM];
    float sm = (ncs + 1e-5f) / (nsum + K_EMB * 1e-5f) * nsum;
    float inv_sm = 1.0f / sm;
    float4 eav = *(const float4*)(embed_avg + e0);
    float4 acc = *(const float4*)(out + OFF_EA + e0);
    float4 ea;
    ea.x = eav.x * 0.99f + 0.01f * acc.x;
    ea.y = eav.y * 0.99f + 0.01f * acc.y;
    ea.z = eav.z * 0.99f + 0.01f * acc.z;
    ea.w = eav.w * 0.99f + 0.01f * acc.w;
    __syncthreads();                        // all cnt reads in block done
    if ((e0 & 63) == 0) out[OFF_CS + k] = ncs;
    *(float4*)(out + OFF_EA + e0) = ea;
    float4 w4;
    w4.x = ea.x * inv_sm; w4.y = ea.y * inv_sm;
    w4.z = ea.z * inv_sm; w4.w = ea.w * inv_sm;
    *(float4*)(out + OFF_W + e0) = w4;
    if (e0 == 0)
      out[OFF_LOSS] = 0.25f * (ws[WS_ZSQ] + ws[WS_LOSS]) * (1.0f / 1048576.0f);
  }
}

// ---------------------------------------------------------------------------
extern "C" void kernel_launch(void* const* d_in, const int* in_sizes, int n_in,
                              void* d_out, int out_size, void* d_ws, size_t ws_size,
                              hipStream_t stream) {
  const float* z = (const float*)d_in[0];
  const float* weight = (const float*)d_in[1];
  const float* cluster = (const float*)d_in[2];
  const float* embed_avg = (const float*)d_in[3];
  float* out = (float*)d_out;
  float* ws = (float*)d_ws;
  float* wnorm = ws + WS_WNORM;
  int* idx = (int*)(ws + WS_IDX);
  int* fcnt = (int*)ws + WS_FCNT;
  const short* Ap = (const short*)out;                     // A' in z_q region
  const short* Bp = (const short*)((unsigned short*)out + B_BASE);
  float* cand = out + OFF_EA;
  unsigned long long* packed = (unsigned long long*)(out + PK_BASE);
  int* flags = (int*)out + SCR_FLAGS;                      // dead-B'' scratch
  int* toklist = (int*)out + SCR_TOK;
  int* offs = (int*)out + SCR_OFFS;
  int* curs = (int*)out + SCR_CURS;

  hipLaunchKernelGGL(k_prep, dim3(768), dim3(256), 0, stream, weight, z, out, ws);
  hipLaunchKernelGGL(k_argmin, dim3(2048), dim3(256), 0, stream,
                     Ap, Bp, wnorm, cand);
  hipLaunchKernelGGL(k_reduce, dim3(N_TOK / 256), dim3(256), 0, stream,
                     cand, flags, fcnt, packed, out + OFF_CS, ws);
  hipLaunchKernelGGL(k_refine, dim3(2048), dim3(256), 0, stream,
                     z, weight, wnorm, flags, fcnt, packed);
  hipLaunchKernelGGL(k_enc, dim3(N_TOK / 256), dim3(256), 0, stream,
                     packed, idx, out + OFF_CS, ws);
  hipLaunchKernelGGL(k_scan, dim3(1), dim3(256), 0, stream,
                     out + OFF_CS, cluster, offs, curs, ws);
  hipLaunchKernelGGL(k_scatter, dim3(N_TOK / 256), dim3(256), 0, stream,
                     idx, curs, toklist);
  hipLaunchKernelGGL(k_embed, dim3(K_EMB), dim3(256), 0, stream,
                     (const unsigned short*)out, out + OFF_CS, offs, toklist,
                     out + OFF_EA);
  hipLaunchKernelGGL(k_quant_final, dim3(1536), dim3(256), 0, stream,
                     z, weight, cluster, embed_avg, idx, out, ws);
}

// Round 19
// 182.843 us; speedup vs baseline: 1.3139x; 1.0286x over previous
//
#include <hip/hip_runtime.h>

// EMA Vector-Quantizer for MI355X (gfx950).
// N=16384 tokens, D=64, K=8192.
// R17-R19: fp32 VALU GEMM plateau 203us. R20-R23: bf16 hi/lo split GEMM on
// matrix pipe + exact-margin fp32 refine. R24: wave-per-code refine.
// R25: atomic-free embed. R26/R29/R30: argmin ~71-73us. R31: embed
// block-per-code. R32 (failed): coop mega-kernel, per-XCD L2 staleness.
// R33: A'-prep re-grid. R34: 16-lane-group refine -> 194.6us.
// R35: SPLIT verdict. Barrier-halving REGRESSED argmin 73->82.5 (pair
// staging: occ 65->41%, all counters worse) -- barrier theory dead; argmin
// is dependency-structure bound at ~73us across 5 structural variants.
// Loss-identity + quant/final fusion PAID: tail 121.6 -> 105.6 (-16us).
// R36 (this): surgical revert of k_argmin to R30 structure (4KB chunks,
// vmcnt(1), LB(256,8) = 8 blocks/CU); keep ALL R35 tail changes (loss via
// distance identity, z^2 partials in prep, d-sum in enc, fused
// k_quant_final, 9 launches). No other changes (no confounds).
// Scratch liveness (out buffer):
//   A' bf16[16384][128] @ 0      : prep -> k_embed, then z_q (quant role)
//   B'' @ float 1056768 (2MB)    : prep -> k_argmin, then int scratch
//     FLAGS@1056768 TOK@1073152 OFFS@1089536 CURS@1097736 (all < CS)
//   cand [EA, +393216) / packed @ PK_BASE : dead before k_embed owns EA
//   counts @ OFF_CS: zeroed in k_reduce -> k_enc -> scan/embed/final role
// Predicted: argmin ~73 (counters match R30/R33), total ~178-181us.

#define N_TOK 16384
#define K_EMB 8192
#define EMB_D 64
#define GROUPS 8

typedef short bf8 __attribute__((ext_vector_type(8)));
typedef float f32x4 __attribute__((ext_vector_type(4)));
typedef unsigned short us4 __attribute__((ext_vector_type(4)));

// d_out flat layout (float32), reference return order:
// z_q (1048576) | loss | new_weight (524288) | new_cluster_size (8192) | new_embed_avg (524288)
#define OFF_LOSS 1048576
#define OFF_W    1048577
#define OFF_CS   1572865
#define OFF_EA   1581057

// scratch offsets
#define B_BASE   2113536   // ushort index into out = byte 4227072 (16B aligned)
#define CAND_I1  131072    // within EA-based cand area (floats/ints)
#define CAND_D2  262144
#define PK_BASE  (OFF_EA + 393217)  // even float idx -> 8B-aligned u64[16384]

// int-indexed scratch in dead-B'' (W region, consumed before k_quant_final)
#define SCR_FLAGS 1056768
#define SCR_TOK   1073152
#define SCR_OFFS  1089536
#define SCR_CURS  1097736

#define MARGIN 0.01f

// ws float offsets
#define WS_NSUM  0
#define WS_LOSS  1
#define WS_FCNT  2        // int
#define WS_ZSQ   3        // sum z^2 (written by scan)
#define WS_WNORM 16
#define WS_IDX   (WS_WNORM + K_EMB)       // int idx[16384]
#define WS_ZSQ_P (WS_IDX + N_TOK)         // 256 per-block z^2 partials

__device__ __forceinline__ unsigned short f2bf(float x) {
  unsigned int b = __float_as_uint(x);
  return (unsigned short)((b + 0x7fff + ((b >> 16) & 1)) >> 16);
}
__device__ __forceinline__ float bf2f(unsigned short h) {
  return __uint_as_float(((unsigned int)h) << 16);
}

// async global->LDS, 16B per lane (dest = wave-uniform base + lane*16)
__device__ __forceinline__ void gload16(const void* g, void* l) {
  __builtin_amdgcn_global_load_lds(
      (const __attribute__((address_space(1))) void*)g,
      (__attribute__((address_space(3))) void*)l, 16, 0, 0);
}

// ---------------------------------------------------------------------------
// K0 (fused): blocks 0..511: wnorm[k] + B'' chunk layout + fcnt zero.
// Blocks 512..767: A' = [bf16_hi | bf16_lo], 64 tokens/block + z^2 partial.
__global__ void k_prep(const float* __restrict__ weight, const float* __restrict__ z,
                       float* __restrict__ out, float* __restrict__ ws) {
  __shared__ float z_s[64 * 64];                  // 16KB (A'-branch only)
  __shared__ float zred[4];
  if (blockIdx.x < 512) {
    int gid = blockIdx.x * 256 + threadIdx.x;     // 0..131071
    int row = gid >> 4;                            // codebook row 0..8191
    int l16 = gid & 15;
    float4 w4 = *(const float4*)(weight + row * EMB_D + l16 * 4);
    float s = w4.x * w4.x + w4.y * w4.y + w4.z * w4.z + w4.w * w4.w;
    #pragma unroll
    for (int off = 8; off > 0; off >>= 1) s += __shfl_xor(s, off, 16);
    if (l16 == 0) ws[WS_WNORM + row] = s;

    float wv[4] = {w4.x, w4.y, w4.z, w4.w};
    us4 hi, lo;
    #pragma unroll
    for (int e = 0; e < 4; ++e) {
      unsigned short h = f2bf(wv[e]);
      hi[e] = h;
      lo[e] = f2bf(wv[e] - bf2f(h));
    }
    int d0 = l16 * 4;
    int jj = d0 & 7;                 // 0 or 4
    int lqp = (d0 >> 3) & 3;
    int sp = d0 >> 5;                // 0 or 1
    unsigned short* bp = (unsigned short*)out + B_BASE
        + (row >> 4) * 2048 + (row & 15) * 8 + lqp * 128 + jj;
    *(us4*)(bp + sp * 512) = hi;
    *(us4*)(bp + (2 + sp) * 512) = lo;

    if (gid == 0) ((int*)ws)[WS_FCNT] = 0;
  } else {
    const int t = threadIdx.x;
    const int pb = blockIdx.x - 512;              // 0..255
    const int b = pb >> 4;                        // batch 0..15
    const int hw0 = (pb & 15) * 64;               // hw chunk of 64
    const float* zb = z + b * 65536 + hw0;
    float zsq = 0.f;
    #pragma unroll
    for (int i = 0; i < 4; ++i) {
      int f4 = i * 256 + t;
      int d = f4 >> 4, c4 = (f4 & 15) * 4;
      float4 v = *(const float4*)(zb + d * 1024 + c4);
      zsq += v.x * v.x + v.y * v.y + v.z * v.z + v.w * v.w;
      *(float4*)(z_s + d * 64 + c4) = v;
    }
    __syncthreads();
    const int tokl = t & 63;
    const int jq = t >> 6;                        // 0..3, wave-uniform
    int tok = b * 1024 + hw0 + tokl;
    unsigned short* ap = (unsigned short*)out + (size_t)tok * 128;
    #pragma unroll
    for (int j = jq * 4; j < jq * 4 + 4; ++j) {
      us4 hi, lo;
      #pragma unroll
      for (int e = 0; e < 4; ++e) {
        float zv = z_s[(j * 4 + e) * 64 + tokl];
        unsigned short h = f2bf(zv);
        hi[e] = h;
        lo[e] = f2bf(zv - bf2f(h));
      }
      *(us4*)(ap + j * 4) = hi;
      *(us4*)(ap + 64 + j * 4) = lo;
    }
    // z^2 partial -> slot pb (race-free: one writer per slot)
    #pragma unroll
    for (int off = 32; off > 0; off >>= 1) zsq += __shfl_xor(zsq, off, 64);
    if ((t & 63) == 0) zred[t >> 6] = zsq;
    __syncthreads();
    if (t == 0) ws[WS_ZSQ_P + pb] = zred[0] + zred[1] + zred[2] + zred[3];
  }
}

// ---------------------------------------------------------------------------
// K1: distance argmin on the matrix pipe (R30 structure, converged ~73us;
// R35's pair-staging regressed and is reverted). 2048 blocks (g=bid&7 XCD
// swizzle), 4 waves x 16 tokens, 8 blocks/CU, triple-buffered 4KB chunks,
// counted vmcnt(1), med3 exact top-2 epilogue.
__global__ __launch_bounds__(256, 8) void k_argmin(
    const short* __restrict__ A, const short* __restrict__ B,
    const float* __restrict__ wnorm, float* __restrict__ cand) {
  __shared__ __align__(16) short wbuf[3][2048];   // 3 x 4KB chunk buffers
  __shared__ __align__(16) float wn_s[1024];      // group wnorm
  const int t = threadIdx.x;
  const int lane = t & 63;
  const int wid = __builtin_amdgcn_readfirstlane(t >> 6);  // 0..3
  const int g = blockIdx.x & 7;
  const int tok_blk = blockIdx.x >> 3;            // 0..255
  const int trow0 = tok_blk * 64 + wid * 16;
  const int lr = lane & 15, lq = lane >> 4;

  bf8 a[4];
  {
    const short* ap = A + (size_t)(trow0 + lr) * 128 + lq * 8;
    #pragma unroll
    for (int s = 0; s < 4; ++s) a[s] = *(const bf8*)(ap + s * 32);
  }

  const short* bsrc = B + (size_t)g * 64 * 2048;

  *(float4*)(wn_s + t * 4) = *(const float4*)(wnorm + g * 1024 + t * 4);
  gload16(bsrc + t * 8, &wbuf[0][0] + t * 8);
  gload16(bsrc + 2048 + t * 8, &wbuf[1][0] + t * 8);
  asm volatile("s_waitcnt vmcnt(1) lgkmcnt(0)" ::: "memory");
  __builtin_amdgcn_s_barrier();

  float d1[4], d2[4]; int i1[4];
  #pragma unroll
  for (int v = 0; v < 4; ++v) { d1[v] = 3.4e38f; d2[v] = 3.4e38f; i1[v] = 0; }

  int cur = 0, stg = 2;
  for (int c = 0; c < 64; ++c) {
    if (c + 2 < 64)
      gload16(bsrc + (c + 2) * 2048 + t * 8, &wbuf[stg][0] + t * 8);

    const short* cb = &wbuf[cur][0] + lq * 128 + lr * 8;
    float wn = wn_s[c * 16 + lr];

    bf8 b0 = *(const bf8*)(cb);
    bf8 b1 = *(const bf8*)(cb + 512);
    f32x4 acc = (f32x4)(0.f);
    acc = __builtin_amdgcn_mfma_f32_16x16x32_bf16(a[0], b0, acc, 0, 0, 0);
    acc = __builtin_amdgcn_mfma_f32_16x16x32_bf16(a[1], b1, acc, 0, 0, 0);
    acc = __builtin_amdgcn_mfma_f32_16x16x32_bf16(a[2], b0, acc, 0, 0, 0);
    acc = __builtin_amdgcn_mfma_f32_16x16x32_bf16(a[3], b1, acc, 0, 0, 0);
    bf8 b2 = *(const bf8*)(cb + 1024);
    bf8 b3 = *(const bf8*)(cb + 1536);
    acc = __builtin_amdgcn_mfma_f32_16x16x32_bf16(a[0], b2, acc, 0, 0, 0);
    acc = __builtin_amdgcn_mfma_f32_16x16x32_bf16(a[1], b3, acc, 0, 0, 0);

    const int code = g * 1024 + c * 16 + lr;
    #pragma unroll
    for (int r = 0; r < 4; ++r) {
      float d = fmaf(-2.f, acc[r], wn);
      d2[r] = __builtin_amdgcn_fmed3f(d1[r], d2[r], d);
      bool lt = d < d1[r];
      d1[r] = fminf(d1[r], d);
      i1[r] = lt ? code : i1[r];
    }

    if (c < 63) {
      if (c + 2 < 64) asm volatile("s_waitcnt vmcnt(1)" ::: "memory");
      else            asm volatile("s_waitcnt vmcnt(0)" ::: "memory");
      __builtin_amdgcn_s_barrier();
    }
    cur = (cur == 2) ? 0 : cur + 1;
    stg = (stg == 2) ? 0 : stg + 1;
  }

  #pragma unroll
  for (int m = 1; m < 16; m <<= 1) {
    #pragma unroll
    for (int v = 0; v < 4; ++v) {
      float od1 = __shfl_xor(d1[v], m, 64);
      float od2 = __shfl_xor(d2[v], m, 64);
      int   oi1 = __shfl_xor(i1[v], m, 64);
      d2[v] = fminf(fminf(d2[v], od2), fmaxf(d1[v], od1));
      bool take = (od1 < d1[v]) || (od1 == d1[v] && oi1 < i1[v]);
      d1[v] = take ? od1 : d1[v];
      i1[v] = take ? oi1 : i1[v];
    }
  }

  if (lr == 0) {                           // lanes 0,16,32,48 (lq = 0..3)
    #pragma unroll
    for (int r = 0; r < 4; ++r) {
      int token = trow0 + lq * 4 + r;
      cand[g * N_TOK + token] = d1[r];
      ((int*)cand)[CAND_I1 + g * N_TOK + token] = i1[r];
      cand[CAND_D2 + g * N_TOK + token] = d2[r];
    }
  }
}

// ---------------------------------------------------------------------------
// K2: merge GROUPS candidates (exact 2-min); packed (idx+dist truth) +
// margin flags; zero counts + WS_LOSS (pre-enc; B'' dead here).
__global__ void k_reduce(const float* __restrict__ cand, int* __restrict__ flags,
                         int* __restrict__ fcnt,
                         unsigned long long* __restrict__ packed,
                         float* __restrict__ cs, float* __restrict__ ws) {
  int n = blockIdx.x * 256 + threadIdx.x;
  if (n < K_EMB) cs[n] = 0.f;              // counts accumulator zero
  if (n == 0) ws[WS_LOSS] = 0.f;
  const int* ci = (const int*)cand + CAND_I1;
  float D1 = cand[n]; int I1 = ci[n]; float D2 = cand[CAND_D2 + n];
  #pragma unroll
  for (int g = 1; g < GROUPS; ++g) {
    float d = cand[g * N_TOK + n];
    int   i = ci[g * N_TOK + n];
    float dd = cand[CAND_D2 + g * N_TOK + n];
    D2 = fminf(fminf(D2, dd), fmaxf(D1, d));
    bool take = (d < D1) || (d == D1 && i < I1);
    D1 = take ? d : D1; I1 = take ? i : I1;
  }
  if (D2 - D1 < MARGIN) {
    packed[n] = ~0ull;                     // refine will atomicMin exact vals
    int p = atomicAdd(fcnt, 1);
    flags[p] = n;
  } else {
    unsigned int bits = __float_as_uint(D1);
    unsigned int u = (bits & 0x80000000u) ? ~bits : (bits | 0x80000000u);
    packed[n] = ((unsigned long long)u << 32) | (unsigned int)I1;
  }
}

// ---------------------------------------------------------------------------
// K2b: exact fp32 refine, 16-lane-group structure (R34).
__global__ void k_refine(const float* __restrict__ z, const float* __restrict__ weight,
                         const float* __restrict__ wnorm, const int* __restrict__ flags,
                         const int* __restrict__ fcnt,
                         unsigned long long* __restrict__ packed) {
  const int cnt = *fcnt;
  const int lane = threadIdx.x & 63;
  const int wv = threadIdx.x >> 6;
  const int lg = lane >> 4;                // group 0..3
  const int ld = lane & 15;                // lane-in-group
  for (int w = blockIdx.x; w < cnt * 8; w += gridDim.x) {
    const int f = w >> 3, sub = w & 7;
    const int n = flags[f];
    const int b = n >> 10, hw = n & 1023;
    const float* zb = z + b * 65536 + hw;
    float4 zf;
    zf.x = zb[(ld * 4 + 0) * 1024];
    zf.y = zb[(ld * 4 + 1) * 1024];
    zf.z = zb[(ld * 4 + 2) * 1024];
    zf.w = zb[(ld * 4 + 3) * 1024];
    float bd = 3.4e38f; int bi = 0;
    const int k0 = sub * 1024 + wv * 256;
    #pragma unroll 4
    for (int i = 0; i < 256; i += 4) {
      const int k = k0 + i + lg;           // this group's code
      const float4 wf = *(const float4*)(weight + k * EMB_D + ld * 4);
      float p = zf.x * wf.x;
      p = fmaf(zf.y, wf.y, p);
      p = fmaf(zf.z, wf.z, p);
      p = fmaf(zf.w, wf.w, p);
      #pragma unroll
      for (int off = 8; off > 0; off >>= 1) p += __shfl_xor(p, off, 16);
      float dist = fmaf(-2.f, p, wnorm[k]);
      if (dist < bd) { bd = dist; bi = k; }   // codes ascend within group
    }
    #pragma unroll
    for (int m = 16; m < 64; m <<= 1) {
      float od = __shfl_xor(bd, m, 64);
      int   oi = __shfl_xor(bi, m, 64);
      bool take = (od < bd) || (od == bd && oi < bi);
      bd = take ? od : bd;
      bi = take ? oi : bi;
    }
    if (lane == 0) {
      unsigned int bits = __float_as_uint(bd);
      unsigned int u = (bits & 0x80000000u) ? ~bits : (bits | 0x80000000u);
      atomicMin(packed + n, ((unsigned long long)u << 32) | (unsigned int)bi);
    }
  }
}

// ---------------------------------------------------------------------------
// K2c: idx + enc counts + loss partials (sum d_n unpacked from packed).
__global__ void k_enc(const unsigned long long* __restrict__ packed,
                      int* __restrict__ idx, float* __restrict__ cnt,
                      float* __restrict__ ws) {
  int n = blockIdx.x * 256 + threadIdx.x;
  unsigned long long pk = packed[n];
  int k = (int)(pk & 0xffffffffull);
  idx[n] = k;
  atomicAdd(cnt + k, 1.0f);
  unsigned int u = (unsigned int)(pk >> 32);
  unsigned int bits = (u & 0x80000000u) ? (u & 0x7fffffffu) : ~u;
  float d = __uint_as_float(bits);
  #pragma unroll
  for (int off = 32; off > 0; off >>= 1) d += __shfl_xor(d, off, 64);
  __shared__ float red[4];
  int lane = threadIdx.x & 63, wv = threadIdx.x >> 6;
  if (lane == 0) red[wv] = d;
  __syncthreads();
  if (threadIdx.x == 0)
    atomicAdd(ws + WS_LOSS, red[0] + red[1] + red[2] + red[3]);
}

// ---------------------------------------------------------------------------
// K2e: exclusive prefix-sum of counts -> offs + cursors; nsum closed-form;
// z^2 partial total.
__global__ void k_scan(const float* __restrict__ cnt,
                       const float* __restrict__ cluster_in,
                       int* __restrict__ offs, int* __restrict__ curs,
                       float* __restrict__ ws) {
  __shared__ int part[256];
  __shared__ float fpart[256];
  __shared__ float zp[256];
  const int t = threadIdx.x;
  const int base = t * 32;
  int local[32];
  int s = 0;
  #pragma unroll
  for (int i = 0; i < 32; ++i) { local[i] = s; s += (int)cnt[base + i]; }
  part[t] = s;
  float csl = 0.f;
  #pragma unroll
  for (int i = 0; i < 32; ++i) csl += cluster_in[base + i];
  fpart[t] = csl;
  zp[t] = ws[WS_ZSQ_P + t];
  __syncthreads();
  if (t == 0) {
    int run = 0;
    for (int i = 0; i < 256; ++i) { int v = part[i]; part[i] = run; run += v; }
    float cs2 = 0.f, zs = 0.f;
    for (int i = 0; i < 256; ++i) { cs2 += fpart[i]; zs += zp[i]; }
    ws[WS_NSUM] = 0.99f * cs2 + 0.01f * (float)N_TOK;
    ws[WS_ZSQ] = zs;
  }
  __syncthreads();
  const int p = part[t];
  #pragma unroll
  for (int i = 0; i < 32; ++i) {
    offs[base + i] = p + local[i];
    curs[base + i] = p + local[i];
  }
}

// ---------------------------------------------------------------------------
// K2f: scatter token ids grouped by code (16K atomics over 8K cursors).
__global__ void k_scatter(const int* __restrict__ idx, int* __restrict__ curs,
                          int* __restrict__ toklist) {
  int n = blockIdx.x * 256 + threadIdx.x;
  int k = idx[n];
  int pos = atomicAdd(curs + k, 1);
  toklist[pos] = n;
}

// ---------------------------------------------------------------------------
// K2g: segmented embed_sum, BLOCK per code (R31 structure).
__global__ void k_embed(const unsigned short* __restrict__ A,
                        const float* __restrict__ cnt,
                        const int* __restrict__ offs,
                        const int* __restrict__ toklist,
                        float* __restrict__ embed) {
  __shared__ float sh[4][EMB_D];
  const int t = threadIdx.x;
  const int lane = t & 63;
  const int w = t >> 6;                    // wave 0..3
  const int k = blockIdx.x;
  const int m = (int)cnt[k];
  const int off = offs[k];

  float sA = 0.f, sB = 0.f;                // pair partials for this lane
  #pragma unroll 2
  for (int i = w; i < m; i += 4) {
    int tok = toklist[off + i];            // wave-uniform -> s_load
    unsigned v = *(const unsigned*)(A + (size_t)tok * 128 + 2 * lane);
    sA += bf2f((unsigned short)(v & 0xffffu));
    sB += bf2f((unsigned short)(v >> 16));
  }
  sA += __shfl_xor(sA, 32, 64);
  sB += __shfl_xor(sB, 32, 64);
  if (lane < 32) {
    sh[w][2 * lane] = sA;
    sh[w][2 * lane + 1] = sB;
  }
  __syncthreads();
  if (t < EMB_D)
    embed[k * EMB_D + t] = sh[0][t] + sh[1][t] + sh[2][t] + sh[3][t];
}

// ---------------------------------------------------------------------------
// K3 (fused quant+final): blocks 0..1023 = quant role (z_q gather, x4).
// Blocks 1024..1535 = final role (cluster+final x4 + loss finalize).
__global__ void k_quant_final(const float* __restrict__ z,
                              const float* __restrict__ weight,
                              const float* __restrict__ cluster_in,
                              const float* __restrict__ embed_avg,
                              const int* __restrict__ idx,
                              float* __restrict__ out,
                              const float* __restrict__ ws) {
  if (blockIdx.x < 1024) {
    int e0 = (blockIdx.x * 256 + threadIdx.x) * 4;
    int c = (e0 >> 10) & 63;
    int n0 = ((e0 >> 16) << 10) | (e0 & 1023);
    int4 kk = *(const int4*)(idx + n0);
    float4 q;
    q.x = weight[kk.x * EMB_D + c];
    q.y = weight[kk.y * EMB_D + c];
    q.z = weight[kk.z * EMB_D + c];
    q.w = weight[kk.w * EMB_D + c];
    *(float4*)(out + e0) = q;             // straight-through value z+(q-z)=q
  } else {
    int e0 = ((blockIdx.x - 1024) * 256 + threadIdx.x) * 4;   // < 524288
    int k = e0 >> 6;
    float cntk = out[OFF_CS + k];           // raw count
    float ncs = cluster_in[k] * 0.99f + 0.01f * cntk;
    float nsum = ws[WS_NSUM];
    float sm = (ncs + 1e-5f) / (nsum + K_EMB * 1e-5f) * nsum;
    float inv_sm = 1.0f / sm;
    float4 eav = *(const float4*)(embed_avg + e0);
    float4 acc = *(const float4*)(out + OFF_EA + e0);
    float4 ea;
    ea.x = eav.x * 0.99f + 0.01f * acc.x;
    ea.y = eav.y * 0.99f + 0.01f * acc.y;
    ea.z = eav.z * 0.99f + 0.01f * acc.z;
    ea.w = eav.w * 0.99f + 0.01f * acc.w;
    __syncthreads();                        // all cnt reads in block done
    if ((e0 & 63) == 0) out[OFF_CS + k] = ncs;
    *(float4*)(out + OFF_EA + e0) = ea;
    float4 w4;
    w4.x = ea.x * inv_sm; w4.y = ea.y * inv_sm;
    w4.z = ea.z * inv_sm; w4.w = ea.w * inv_sm;
    *(float4*)(out + OFF_W + e0) = w4;
    if (e0 == 0)
      out[OFF_LOSS] = 0.25f * (ws[WS_ZSQ] + ws[WS_LOSS]) * (1.0f / 1048576.0f);
  }
}

// ---------------------------------------------------------------------------
extern "C" void kernel_launch(void* const* d_in, const int* in_sizes, int n_in,
                              void* d_out, int out_size, void* d_ws, size_t ws_size,
                              hipStream_t stream) {
  const float* z = (const float*)d_in[0];
  const float* weight = (const float*)d_in[1];
  const float* cluster = (const float*)d_in[2];
  const float* embed_avg = (const float*)d_in[3];
  float* out = (float*)d_out;
  float* ws = (float*)d_ws;
  float* wnorm = ws + WS_WNORM;
  int* idx = (int*)(ws + WS_IDX);
  int* fcnt = (int*)ws + WS_FCNT;
  const short* Ap = (const short*)out;                     // A' in z_q region
  const short* Bp = (const short*)((unsigned short*)out + B_BASE);
  float* cand = out + OFF_EA;
  unsigned long long* packed = (unsigned long long*)(out + PK_BASE);
  int* flags = (int*)out + SCR_FLAGS;                      // dead-B'' scratch
  int* toklist = (int*)out + SCR_TOK;
  int* offs = (int*)out + SCR_OFFS;
  int* curs = (int*)out + SCR_CURS;

  hipLaunchKernelGGL(k_prep, dim3(768), dim3(256), 0, stream, weight, z, out, ws);
  hipLaunchKernelGGL(k_argmin, dim3(2048), dim3(256), 0, stream,
                     Ap, Bp, wnorm, cand);
  hipLaunchKernelGGL(k_reduce, dim3(N_TOK / 256), dim3(256), 0, stream,
                     cand, flags, fcnt, packed, out + OFF_CS, ws);
  hipLaunchKernelGGL(k_refine, dim3(2048), dim3(256), 0, stream,
                     z, weight, wnorm, flags, fcnt, packed);
  hipLaunchKernelGGL(k_enc, dim3(N_TOK / 256), dim3(256), 0, stream,
                     packed, idx, out + OFF_CS, ws);
  hipLaunchKernelGGL(k_scan, dim3(1), dim3(256), 0, stream,
                     out + OFF_CS, cluster, offs, curs, ws);
  hipLaunchKernelGGL(k_scatter, dim3(N_TOK / 256), dim3(256), 0, stream,
                     idx, curs, toklist);
  hipLaunchKernelGGL(k_embed, dim3(K_EMB), dim3(256), 0, stream,
                     (const unsigned short*)out, out + OFF_CS, offs, toklist,
                     out + OFF_EA);
  hipLaunchKernelGGL(k_quant_final, dim3(1536), dim3(256), 0, stream,
                     z, weight, cluster, embed_avg, idx, out, ws);
}